// Round 4
// baseline (800.158 us; speedup 1.0000x reference)
//
#include <hip/hip_runtime.h>
#include <math.h>

#define NN 1024
#define BB 8
#define NS_ITERS 10
#define EPS_SHIFT 4.0f
#define MB (1u<<20)

typedef __attribute__((ext_vector_type(8))) short short8;
typedef __attribute__((ext_vector_type(4))) float floatx4;

__device__ __forceinline__ ushort f2bf(float f) {
    union { float f; uint32_t u; } v; v.f = f;
    uint32_t u = v.u;
    uint32_t r = (u + 0x7fffu + ((u >> 16) & 1u)) >> 16;
    return (ushort)r;
}
__device__ __forceinline__ float bf2f(ushort h) {
    union { uint32_t u; float f; } v; v.u = ((uint32_t)h) << 16;
    return v.f;
}

// async global->LDS, 16B per lane (dest = wave-uniform base + lane*16)
__device__ __forceinline__ void gload16(const ushort* g, ushort* s) {
    __builtin_amdgcn_global_load_lds(
        (__attribute__((address_space(1))) unsigned int*)(g),
        (__attribute__((address_space(3))) unsigned int*)(s), 16, 0, 0);
}

// ---------- block reduction helper (result valid on thread 0) ----------
__device__ __forceinline__ float block_sum(float v) {
    #pragma unroll
    for (int off = 32; off > 0; off >>= 1) v += __shfl_down(v, off, 64);
    __shared__ float red[4];
    int lane = threadIdx.x & 63, wid = threadIdx.x >> 6;
    if (lane == 0) red[wid] = v;
    __syncthreads();
    float t = 0.f;
    if (threadIdx.x == 0) t = red[0] + red[1] + red[2] + red[3];
    return t;
}

// ---------- power iteration pieces: y[row] = sum_j |pu[row][j]| * x[j] ----------
__global__ __launch_bounds__(256) void matvec_abs(const float* __restrict__ pu,
                                                  const float* __restrict__ x,
                                                  float* __restrict__ y,
                                                  int use_ones) {
    int row = blockIdx.x;
    const float4* pr = (const float4*)(pu + (size_t)row * NN);
    float4 p = pr[threadIdx.x];
    float s;
    if (use_ones) {
        s = fabsf(p.x) + fabsf(p.y) + fabsf(p.z) + fabsf(p.w);
    } else {
        float4 xx = ((const float4*)x)[threadIdx.x];
        s = fabsf(p.x) * xx.x + fabsf(p.y) * xx.y + fabsf(p.z) * xx.z + fabsf(p.w) * xx.w;
    }
    s = block_sum(s);
    if (threadIdx.x == 0) y[row] = s;
}

__global__ void norm_vec(const float* __restrict__ y, float* __restrict__ v) {
    float ss = 0.f;
    for (int i = threadIdx.x; i < NN; i += 256) { float t = y[i]; ss += t * t; }
    #pragma unroll
    for (int off = 32; off > 0; off >>= 1) ss += __shfl_down(ss, off, 64);
    __shared__ float red[4];
    __shared__ float s_inv;
    int lane = threadIdx.x & 63, wid = threadIdx.x >> 6;
    if (lane == 0) red[wid] = ss;
    __syncthreads();
    if (threadIdx.x == 0) s_inv = rsqrtf(red[0] + red[1] + red[2] + red[3]);
    __syncthreads();
    float inv = s_inv;
    for (int i = threadIdx.x; i < NN; i += 256) v[i] = y[i] * inv;
}

__global__ void dot_vec(const float* __restrict__ a, const float* __restrict__ b,
                        float* __restrict__ out) {
    float s = 0.f;
    for (int i = threadIdx.x; i < NN; i += 256) s += a[i] * b[i];
    s = block_sum(s);
    if (threadIdx.x == 0) out[0] = s;
}

// ---------- deflation: D = N*(|pu| - v w^T - w v^T + lam v v^T) + eps*I ----------
__global__ __launch_bounds__(256) void deflate_kernel(const float* __restrict__ pu,
                                                      const float* __restrict__ v,
                                                      const float* __restrict__ w,
                                                      float* __restrict__ sc,
                                                      float* __restrict__ D) {
    int idx = blockIdx.x * 256 + threadIdx.x;   // over NN*NN/4
    int row = idx >> 8;
    int c0 = (idx & 255) << 2;
    float lam = sc[5];
    float vr = v[row], wr = w[row];
    float4 p = ((const float4*)pu)[idx];
    float4 vc = *(const float4*)(v + c0);
    float4 wc = *(const float4*)(w + c0);
    float4 d;
    d.x = (float)NN * (fabsf(p.x) - vr * wc.x - wr * vc.x + lam * vr * vc.x);
    d.y = (float)NN * (fabsf(p.y) - vr * wc.y - wr * vc.y + lam * vr * vc.y);
    d.z = (float)NN * (fabsf(p.z) - vr * wc.z - wr * vc.z + lam * vr * vc.z);
    d.w = (float)NN * (fabsf(p.w) - vr * wc.w - wr * vc.w + lam * vr * vc.w);
    int dd = row - c0;
    if (dd == 0) d.x += EPS_SHIFT;
    else if (dd == 1) d.y += EPS_SHIFT;
    else if (dd == 2) d.z += EPS_SHIFT;
    else if (dd == 3) d.w += EPS_SHIFT;
    ((float4*)D)[idx] = d;
    float ss = d.x * d.x + d.y * d.y + d.z * d.z + d.w * d.w;
    ss = block_sum(ss);
    if (threadIdx.x == 0) atomicAdd(sc, ss);
}

// sc[0]=||D||_F^2, sc[5]=lam~  ->  sc[1]=1/c, sc[2]=sqrt(c), sc[4]=sqrt(N*lam~)
__global__ void finalize_kernel(float* sc) {
    float c = sqrtf(sc[0]);
    sc[1] = 1.f / c;
    sc[2] = sqrtf(c);
    sc[4] = sqrtf((float)NN * sc[5]);
}

// ---------- MFMA GEMM: 128x128 tile, 256 threads (4 waves, 2x2 quadrants) ------
// Staging-BW-bound regime (R1-R3 evidence): halve staged bytes with 128^2 tiles
// (each block stages 1MB over K=1024; 64 blocks = 64MB/unit vs 128MB at 64^2),
// and XCD-patch-swizzle the 8x8 tile grid so each XCD's staging working set
// (A 2 tile-rows = 1MB, B 4 tile-cols = 2MB) fits its 4MB L2.
// Staging lane map: 4 lanes per row read one 64B segment (coalesced, R1-proven).
// Fragment reads keep R1's layout (4-way alias proven non-binding in R3).
__device__ __forceinline__ void mm_dev(const ushort* __restrict__ Ah,
                                       const ushort* __restrict__ Al,
                                       const ushort* __restrict__ Bh,
                                       const ushort* __restrict__ Bl,
                                       int row0, int col0, int kb, int kc,
                                       float* __restrict__ Cf,
                                       ushort* __restrict__ Chi,
                                       ushort* __restrict__ Clo) {
    // 2 buffers x 4 tiles (Ah,Al,Bh,Bl) x 128x32 bf16 (8KB) = 64 KiB
    __shared__ __align__(16) ushort lds[2 * 4 * 4096];
    const int t = threadIdx.x;          // 0..255
    const int w = t >> 6, l = t & 63;
    const int wr = ((w >> 1) & 1) << 6; // wave row quadrant: 0 or 64
    const int wc = (w & 1) << 6;        // wave col quadrant: 0 or 64
    const int fm = l & 15, fq = l >> 4;
    const int srow = l >> 2;            // 0..15 staging row within issue
    const int scol = (l & 3) << 3;      // 8 bf16 = 16B slot within 64B row seg

    // wave w stages tile w (0=Ah,1=Al,2=Bh,3=Bl) with 8 DMA issues
    const ushort* gsrc = (w == 0) ? Ah : (w == 1) ? Al : (w == 2) ? Bh : Bl;
    const int r0 = (w < 2) ? row0 : col0;
    const ushort* gp = gsrc + (size_t)(r0 + srow) * NN + kb + scol;

    floatx4 acc[4][4];
    #pragma unroll
    for (int mi = 0; mi < 4; ++mi)
        #pragma unroll
        for (int ni = 0; ni < 4; ++ni) acc[mi][ni] = (floatx4)0.f;

    auto STAGE = [&](int bufi, int koff) {
        ushort* sb = lds + (bufi << 14) + (w << 12);
        #pragma unroll
        for (int rb = 0; rb < 8; ++rb)                // 16 rows per issue
            gload16(gp + (size_t)(rb << 4) * NN + koff, sb + (rb << 9));
    };

    // 48 MFMAs per wave on buffer bufi: acc += Ah*Bh + Al*Bh + Ah*Bl
    auto COMPUTE = [&](int bufi) {
        const ushort* Ash = lds + (bufi << 14);
        const ushort* Asl = Ash + 4096;
        const ushort* Bsh = Ash + 8192;
        const ushort* Bsl = Ash + 12288;
        short8 ah[4], al[4], bh[4], bl[4];
        #pragma unroll
        for (int i = 0; i < 4; ++i) {
            const int ra = ((wr + (i << 4) + fm) << 5) + (fq << 3);
            const int rb = ((wc + (i << 4) + fm) << 5) + (fq << 3);
            ah[i] = *(const short8*)&Ash[ra];
            al[i] = *(const short8*)&Asl[ra];
            bh[i] = *(const short8*)&Bsh[rb];
            bl[i] = *(const short8*)&Bsl[rb];
        }
        #pragma unroll
        for (int mi = 0; mi < 4; ++mi)
            #pragma unroll
            for (int ni = 0; ni < 4; ++ni) {
                acc[mi][ni] = __builtin_amdgcn_mfma_f32_16x16x32_bf16(ah[mi], bh[ni], acc[mi][ni], 0, 0, 0);
                acc[mi][ni] = __builtin_amdgcn_mfma_f32_16x16x32_bf16(al[mi], bh[ni], acc[mi][ni], 0, 0, 0);
                acc[mi][ni] = __builtin_amdgcn_mfma_f32_16x16x32_bf16(ah[mi], bl[ni], acc[mi][ni], 0, 0, 0);
            }
    };

    const int nk = kc >> 5;             // 16 (stage1) or 32 (full K); always even
    STAGE(0, 0);
    __syncthreads();                    // drains vmcnt(0) + barrier
    #pragma unroll 1
    for (int kt = 0; kt < nk; kt += 2) {
        STAGE(1, (kt + 1) << 5);        // prefetch odd step under even compute
        COMPUTE(0);
        __syncthreads();
        if (kt + 2 < nk) STAGE(0, (kt + 2) << 5);
        COMPUTE(1);
        __syncthreads();
    }

    // epilogue: C/D layout col=lane&15, row=(lane>>4)*4+reg (m89-verified)
    #pragma unroll
    for (int mi = 0; mi < 4; ++mi) {
        #pragma unroll
        for (int r = 0; r < 4; ++r) {
            int row = row0 + wr + (mi << 4) + (fq << 2) + r;
            #pragma unroll
            for (int ni = 0; ni < 4; ++ni) {
                int col = col0 + wc + (ni << 4) + fm;
                float v = acc[mi][ni][r];
                size_t idx = (size_t)row * NN + col;
                if (Cf) {
                    Cf[idx] = v;
                } else {
                    ushort h = f2bf(v);
                    Chi[idx] = h;
                    Clo[idx] = f2bf(v - bf2f(h));
                }
            }
        }
    }
}

// XCD patch swizzle over the 8x8 tile grid: XCD p (~blockIdx.x under round-
// robin dispatch) owns a 2x4 tile patch -> per-XCD staging set ~3MB <= 4MB L2.
__device__ __forceinline__ void tile_swizzle(int& row0, int& col0) {
    int flat = blockIdx.y * 8 + blockIdx.x;
    int p = flat & 7;          // ~XCD id
    int i = flat >> 3;         // 0..7 within patch
    int by = ((p >> 1) << 1) + (i >> 2);   // 2 tile-rows per patch
    int bx = ((p & 1) << 2) + (i & 3);     // 4 tile-cols per patch
    row0 = by << 7;
    col0 = bx << 7;
}

// stage-1: Mp[z] = partial (Z*Y) over half the K range (fp32 partials, no atomics)
__global__ __launch_bounds__(256, 2) void k_stage1(const ushort* __restrict__ Zh,
                                                   const ushort* __restrict__ Zl,
                                                   const ushort* __restrict__ Yh,
                                                   const ushort* __restrict__ Yl,
                                                   float* __restrict__ Mp) {
    int s = blockIdx.z;
    int row0, col0; tile_swizzle(row0, col0);
    mm_dev(Zh, Zl, Yh, Yl, row0, col0,
           s * (NN / 2), NN / 2, Mp + (size_t)s * NN * NN, nullptr, nullptr);
}

// stage-2: z=0: Yn = Y*W ; z=1: Zn = W*Z  (epilogue writes bf16 hi/lo directly)
__global__ __launch_bounds__(256, 2) void k_stage2(const ushort* __restrict__ Yh,
                                                   const ushort* __restrict__ Yl,
                                                   const ushort* __restrict__ Wh,
                                                   const ushort* __restrict__ Wl,
                                                   const ushort* __restrict__ Zh,
                                                   const ushort* __restrict__ Zl,
                                                   ushort* __restrict__ Ynh,
                                                   ushort* __restrict__ Ynl,
                                                   ushort* __restrict__ Znh,
                                                   ushort* __restrict__ Znl) {
    int row0, col0; tile_swizzle(row0, col0);
    if (blockIdx.z == 0)
        mm_dev(Yh, Yl, Wh, Wl, row0, col0, 0, NN, nullptr, Ynh, Ynl);
    else
        mm_dev(Wh, Wl, Zh, Zl, row0, col0, 0, NN, nullptr, Znh, Znl);
}

// final: Yf = Y*W in fp32
__global__ __launch_bounds__(256, 2) void k_final(const ushort* __restrict__ Yh,
                                                  const ushort* __restrict__ Yl,
                                                  const ushort* __restrict__ Wh,
                                                  const ushort* __restrict__ Wl,
                                                  float* __restrict__ Yf) {
    int row0, col0; tile_swizzle(row0, col0);
    mm_dev(Yh, Yl, Wh, Wl, row0, col0, 0, NN, Yf, nullptr, nullptr);
}

// W = 1.5I - 0.25*(Mp0+Mp1+Mp0^T+Mp1^T) -> bf16 hi/lo  (symmetrized M)
__global__ __launch_bounds__(256) void k_wsplit(const float* __restrict__ Mp,
                                                ushort* __restrict__ Wh,
                                                ushort* __restrict__ Wl) {
    int i = blockIdx.x * 256 + threadIdx.x;     // float4 index over NN*NN/4
    int row = i >> 8, c0 = (i & 255) << 2;
    float4 m0 = ((const float4*)Mp)[i];
    float4 m1 = ((const float4*)Mp)[i + NN * NN / 4];
    float mr[4] = {m0.x + m1.x, m0.y + m1.y, m0.z + m1.z, m0.w + m1.w};
    float wv[4];
    #pragma unroll
    for (int j = 0; j < 4; ++j) {
        float mt = Mp[(size_t)(c0 + j) * NN + row] +
                   Mp[(size_t)(c0 + j) * NN + row + (size_t)NN * NN];
        wv[j] = -0.25f * (mr[j] + mt);
    }
    int dd = row - c0;
    if (dd >= 0 && dd < 4) wv[dd] += 1.5f;
    ushort4 hv, lv;
    ushort* hp = (ushort*)&hv; ushort* lp = (ushort*)&lv;
    #pragma unroll
    for (int j = 0; j < 4; ++j) {
        ushort h = f2bf(wv[j]); hp[j] = h; lp[j] = f2bf(wv[j] - bf2f(h));
    }
    *(ushort4*)&Wh[(size_t)i << 2] = hv;
    *(ushort4*)&Wl[(size_t)i << 2] = lv;
}

// iter0: Y0 = D/c -> split ; W0 = 1.5I - 0.5*Y0 -> split
__global__ __launch_bounds__(256) void k_wsplit0(const float* __restrict__ D,
                                                 const float* __restrict__ sc,
                                                 ushort* __restrict__ Yh,
                                                 ushort* __restrict__ Yl,
                                                 ushort* __restrict__ Wh,
                                                 ushort* __restrict__ Wl) {
    int i = blockIdx.x * 256 + threadIdx.x;
    int row = i >> 8, c0 = (i & 255) << 2;
    float invc = sc[1];
    float4 d = ((const float4*)D)[i];
    float yv[4] = {d.x * invc, d.y * invc, d.z * invc, d.w * invc};
    ushort4 yh, yl, wh, wl;
    ushort* yhp = (ushort*)&yh; ushort* ylp = (ushort*)&yl;
    ushort* whp = (ushort*)&wh; ushort* wlp = (ushort*)&wl;
    int dd = row - c0;
    #pragma unroll
    for (int j = 0; j < 4; ++j) {
        float y = yv[j];
        ushort h = f2bf(y); yhp[j] = h; ylp[j] = f2bf(y - bf2f(h));
        float wv = ((dd == j) ? 1.5f : 0.f) - 0.5f * y;
        ushort h2 = f2bf(wv); whp[j] = h2; wlp[j] = f2bf(wv - bf2f(h2));
    }
    *(ushort4*)&Yh[(size_t)i << 2] = yh;
    *(ushort4*)&Yl[(size_t)i << 2] = yl;
    *(ushort4*)&Wh[(size_t)i << 2] = wh;
    *(ushort4*)&Wl[(size_t)i << 2] = wl;
}

// out0[b][n][m] = d_b[n]*d_b[m] + |P_u[n,m]| + 0.01*Q_k[n,m]^2 ; d_b = x[0,:]-x[b,:]
__global__ __launch_bounds__(256) void out0_kernel(const float* __restrict__ x,
                                                   const float* __restrict__ pu,
                                                   const float* __restrict__ qk,
                                                   float* __restrict__ out) {
    int i = blockIdx.x * blockDim.x + threadIdx.x;  // over BB*NN*NN/4
    int rem = i & (NN * NN / 4 - 1);
    int b = i >> 18;
    int n = rem >> 8;
    int m4 = (rem & 255) << 2;
    float dn = x[n] - x[b * NN + n];
    float4 x0v = *(const float4*)(x + m4);
    float4 xbv = *(const float4*)(x + b * NN + m4);
    float4 pv = ((const float4*)pu)[rem];
    float4 qv = ((const float4*)qk)[rem];
    float4 o;
    o.x = dn * (x0v.x - xbv.x) + fabsf(pv.x) + 0.01f * qv.x * qv.x;
    o.y = dn * (x0v.y - xbv.y) + fabsf(pv.y) + 0.01f * qv.y * qv.y;
    o.z = dn * (x0v.z - xbv.z) + fabsf(pv.z) + 0.01f * qv.z * qv.z;
    o.w = dn * (x0v.w - xbv.w) + fabsf(pv.w) + 0.01f * qv.w * qv.w;
    ((float4*)out)[i] = o;
}

// fused sym + out1: p[j][i] = 0.5*sqrt(c)*(Yf[j][i]+Yf[i][j]) + sqrt(N*lam)*v[j]*v[i]
// out1[0][b][j][i] = x[b][i] + p ; out1[0][b][N+j][i] = x[b][i] - p
__global__ __launch_bounds__(256) void k_out1(const float* __restrict__ x,
                                              const float* __restrict__ Yf,
                                              const float* __restrict__ sc,
                                              const float* __restrict__ v,
                                              float* __restrict__ out1) {
    int i = blockIdx.x * 256 + threadIdx.x;     // over NN*NN/4
    int j = i >> 8, i0 = (i & 255) << 2;
    float s = 0.5f * sc[2], s1v = sc[4] * v[j];
    float4 yr = *(const float4*)(Yf + (size_t)j * NN + i0);
    float yc0 = Yf[(size_t)(i0 + 0) * NN + j];
    float yc1 = Yf[(size_t)(i0 + 1) * NN + j];
    float yc2 = Yf[(size_t)(i0 + 2) * NN + j];
    float yc3 = Yf[(size_t)(i0 + 3) * NN + j];
    float4 vc = *(const float4*)(v + i0);
    float4 p;
    p.x = s * (yr.x + yc0) + s1v * vc.x;
    p.y = s * (yr.y + yc1) + s1v * vc.y;
    p.z = s * (yr.z + yc2) + s1v * vc.z;
    p.w = s * (yr.w + yc3) + s1v * vc.w;
    #pragma unroll
    for (int b = 0; b < BB; ++b) {
        float4 xv = *(const float4*)(x + b * NN + i0);
        float4 a, m;
        a.x = xv.x + p.x; a.y = xv.y + p.y; a.z = xv.z + p.z; a.w = xv.w + p.w;
        m.x = xv.x - p.x; m.y = xv.y - p.y; m.z = xv.z - p.z; m.w = xv.w - p.w;
        float* base = out1 + (size_t)b * 2 * NN * NN;
        *(float4*)(base + (size_t)j * NN + i0) = a;
        *(float4*)(base + (size_t)(NN + j) * NN + i0) = m;
    }
}

extern "C" void kernel_launch(void* const* d_in, const int* in_sizes, int n_in,
                              void* d_out, int out_size, void* d_ws, size_t ws_size,
                              hipStream_t stream) {
    const float* x  = (const float*)d_in[0];
    const float* pu = (const float*)d_in[1];
    const float* qk = (const float*)d_in[2];
    float* out = (float*)d_out;
    char* ws = (char*)d_ws;

    // layout: [0,8MB) fp32 Mp0/Mp1 (Mp0 doubles as D before iter1 and Yf after
    // last wsplit); [8MB,28MB) five bf16 hi/lo pairs (4MB each); vectors after.
    float* Mp = (float*)ws;
    float* D  = Mp;
    float* Yf = Mp;
    ushort* hi[5]; ushort* lo[5];
    for (int k = 0; k < 5; ++k) {
        hi[k] = (ushort*)(ws + (size_t)8 * MB + (size_t)k * 4 * MB);
        lo[k] = (ushort*)(ws + (size_t)8 * MB + (size_t)k * 4 * MB + 2 * MB);
    }
    float* vv = (float*)(ws + (size_t)28 * MB);
    float* vw = (float*)(ws + (size_t)28 * MB + 4096);
    float* vt = (float*)(ws + (size_t)28 * MB + 8192);
    float* sc = (float*)(ws + (size_t)28 * MB + 12288);

    // ---- deflation: top eigpair of |P_u| via 3 matvecs ----
    hipMemsetAsync(sc, 0, 64, stream);
    matvec_abs<<<NN, 256, 0, stream>>>(pu, vv, vt, 1);
    norm_vec<<<1, 256, 0, stream>>>(vt, vv);
    matvec_abs<<<NN, 256, 0, stream>>>(pu, vv, vt, 0);
    norm_vec<<<1, 256, 0, stream>>>(vt, vv);
    matvec_abs<<<NN, 256, 0, stream>>>(pu, vv, vw, 0);
    dot_vec<<<1, 256, 0, stream>>>(vv, vw, sc + 5);
    deflate_kernel<<<NN * NN / 4 / 256, 256, 0, stream>>>(pu, vv, vw, sc, D);
    finalize_kernel<<<1, 1, 0, stream>>>(sc);

    // ---- iter 0: Y0,W0 from D; Y1 = Y0*W0 ; Z1 = W0 (pointer swap) ----
    k_wsplit0<<<NN * NN / 4 / 256, 256, 0, stream>>>(D, sc, hi[0], lo[0], hi[1], lo[1]);
    k_stage2<<<dim3(8, 8, 1), 256, 0, stream>>>(hi[0], lo[0], hi[1], lo[1],
                                                hi[0], lo[0],   // Z unused (z=0 only)
                                                hi[2], lo[2], hi[3], lo[3]);
    int Y = 2, Z = 1, f0 = 0, f1 = 3, f2 = 4;

    // ---- iters 1..NS_ITERS-1 ----
    for (int it = 1; it < NS_ITERS; ++it) {
        int W = f0;
        k_stage1<<<dim3(8, 8, 2), 256, 0, stream>>>(hi[Z], lo[Z], hi[Y], lo[Y], Mp);
        k_wsplit<<<NN * NN / 4 / 256, 256, 0, stream>>>(Mp, hi[W], lo[W]);
        if (it + 1 < NS_ITERS) {
            int Yn = f1, Zn = f2;
            k_stage2<<<dim3(8, 8, 2), 256, 0, stream>>>(
                hi[Y], lo[Y], hi[W], lo[W], hi[Z], lo[Z],
                hi[Yn], lo[Yn], hi[Zn], lo[Zn]);
            f0 = Y; f1 = Z; f2 = W;
            Y = Yn; Z = Zn;
        } else {
            k_final<<<dim3(8, 8, 1), 256, 0, stream>>>(hi[Y], lo[Y], hi[W], lo[W], Yf);
        }
    }

    // ---- outputs ----
    out0_kernel<<<(BB * NN * NN / 4) / 256, 256, 0, stream>>>(x, pu, qk, out);
    k_out1<<<NN * NN / 4 / 256, 256, 0, stream>>>(x, Yf, sc, vv,
                                                  out + (size_t)BB * NN * NN);
}

// Round 5
// 646.010 us; speedup vs baseline: 1.2386x; 1.2386x over previous
//
#include <hip/hip_runtime.h>
#include <math.h>

#define NN 1024
#define BB 8
#define NS_ITERS 10
#define EPS_SHIFT 4.0f
#define MB (1u<<20)

typedef __attribute__((ext_vector_type(8))) short short8;
typedef __attribute__((ext_vector_type(4))) float floatx4;

__device__ __forceinline__ ushort f2bf(float f) {
    union { float f; uint32_t u; } v; v.f = f;
    uint32_t u = v.u;
    uint32_t r = (u + 0x7fffu + ((u >> 16) & 1u)) >> 16;
    return (ushort)r;
}
__device__ __forceinline__ float bf2f(ushort h) {
    union { uint32_t u; float f; } v; v.u = ((uint32_t)h) << 16;
    return v.f;
}

// async global->LDS, 16B per lane (dest = wave-uniform base + lane*16)
__device__ __forceinline__ void gload16(const ushort* g, ushort* s) {
    __builtin_amdgcn_global_load_lds(
        (__attribute__((address_space(1))) unsigned int*)(g),
        (__attribute__((address_space(3))) unsigned int*)(s), 16, 0, 0);
}

// ---------- block reduction helper (result valid on thread 0) ----------
__device__ __forceinline__ float block_sum(float v) {
    #pragma unroll
    for (int off = 32; off > 0; off >>= 1) v += __shfl_down(v, off, 64);
    __shared__ float red[4];
    int lane = threadIdx.x & 63, wid = threadIdx.x >> 6;
    if (lane == 0) red[wid] = v;
    __syncthreads();
    float t = 0.f;
    if (threadIdx.x == 0) t = red[0] + red[1] + red[2] + red[3];
    return t;
}

// ---------- power iteration pieces: y[row] = sum_j |pu[row][j]| * x[j] ----------
__global__ __launch_bounds__(256) void matvec_abs(const float* __restrict__ pu,
                                                  const float* __restrict__ x,
                                                  float* __restrict__ y,
                                                  int use_ones) {
    int row = blockIdx.x;
    const float4* pr = (const float4*)(pu + (size_t)row * NN);
    float4 p = pr[threadIdx.x];
    float s;
    if (use_ones) {
        s = fabsf(p.x) + fabsf(p.y) + fabsf(p.z) + fabsf(p.w);
    } else {
        float4 xx = ((const float4*)x)[threadIdx.x];
        s = fabsf(p.x) * xx.x + fabsf(p.y) * xx.y + fabsf(p.z) * xx.z + fabsf(p.w) * xx.w;
    }
    s = block_sum(s);
    if (threadIdx.x == 0) y[row] = s;
}

__global__ void norm_vec(const float* __restrict__ y, float* __restrict__ v) {
    float ss = 0.f;
    for (int i = threadIdx.x; i < NN; i += 256) { float t = y[i]; ss += t * t; }
    #pragma unroll
    for (int off = 32; off > 0; off >>= 1) ss += __shfl_down(ss, off, 64);
    __shared__ float red[4];
    __shared__ float s_inv;
    int lane = threadIdx.x & 63, wid = threadIdx.x >> 6;
    if (lane == 0) red[wid] = ss;
    __syncthreads();
    if (threadIdx.x == 0) s_inv = rsqrtf(red[0] + red[1] + red[2] + red[3]);
    __syncthreads();
    float inv = s_inv;
    for (int i = threadIdx.x; i < NN; i += 256) v[i] = y[i] * inv;
}

__global__ void dot_vec(const float* __restrict__ a, const float* __restrict__ b,
                        float* __restrict__ out) {
    float s = 0.f;
    for (int i = threadIdx.x; i < NN; i += 256) s += a[i] * b[i];
    s = block_sum(s);
    if (threadIdx.x == 0) out[0] = s;
}

// ---------- deflation: D = N*(|pu| - v w^T - w v^T + lam v v^T) + eps*I ----------
__global__ __launch_bounds__(256) void deflate_kernel(const float* __restrict__ pu,
                                                      const float* __restrict__ v,
                                                      const float* __restrict__ w,
                                                      float* __restrict__ sc,
                                                      float* __restrict__ D) {
    int idx = blockIdx.x * 256 + threadIdx.x;   // over NN*NN/4
    int row = idx >> 8;
    int c0 = (idx & 255) << 2;
    float lam = sc[5];
    float vr = v[row], wr = w[row];
    float4 p = ((const float4*)pu)[idx];
    float4 vc = *(const float4*)(v + c0);
    float4 wc = *(const float4*)(w + c0);
    float4 d;
    d.x = (float)NN * (fabsf(p.x) - vr * wc.x - wr * vc.x + lam * vr * vc.x);
    d.y = (float)NN * (fabsf(p.y) - vr * wc.y - wr * vc.y + lam * vr * vc.y);
    d.z = (float)NN * (fabsf(p.z) - vr * wc.z - wr * vc.z + lam * vr * vc.z);
    d.w = (float)NN * (fabsf(p.w) - vr * wc.w - wr * vc.w + lam * vr * vc.w);
    int dd = row - c0;
    if (dd == 0) d.x += EPS_SHIFT;
    else if (dd == 1) d.y += EPS_SHIFT;
    else if (dd == 2) d.z += EPS_SHIFT;
    else if (dd == 3) d.w += EPS_SHIFT;
    ((float4*)D)[idx] = d;
    float ss = d.x * d.x + d.y * d.y + d.z * d.z + d.w * d.w;
    ss = block_sum(ss);
    if (threadIdx.x == 0) atomicAdd(sc, ss);
}

// sc[0]=||D||_F^2, sc[5]=lam~  ->  sc[1]=1/c, sc[2]=sqrt(c), sc[4]=sqrt(N*lam~)
__global__ void finalize_kernel(float* sc) {
    float c = sqrtf(sc[0]);
    sc[1] = 1.f / c;
    sc[2] = sqrtf(c);
    sc[4] = sqrtf((float)NN * sc[5]);
}

// ---------- MFMA GEMM: 64x64 tile, 128 threads (2 waves), split-bf16 fp32 ----------
// R1 structure + T3/T4 counted-vmcnt pipeline: 4 LDS buffers, prefetch depth 3,
// ONE raw s_barrier per k-step, s_waitcnt vmcnt(16) (= 2 stages x 8 loads/wave
// still in flight) instead of the vmcnt(0) drain __syncthreads imposes.
// Stage(t+3) goes into buffer (t-1)%4, which every wave finished reading before
// the barrier. Accumulation order identical to R1 -> same numerics.
__device__ __forceinline__ void mm_dev(const ushort* __restrict__ Ah,
                                       const ushort* __restrict__ Al,
                                       const ushort* __restrict__ Bh,
                                       const ushort* __restrict__ Bl,
                                       int row0, int col0, int kb, int kc,
                                       float* __restrict__ Cf,
                                       ushort* __restrict__ Chi,
                                       ushort* __restrict__ Clo) {
    // 4 buffers x 4 tiles (Ah,Al,Bh,Bl) x 64x32 bf16 = 64 KiB
    __shared__ __align__(16) ushort lds[4 * 4 * 2048];
    const int t = threadIdx.x;          // 0..127
    const int w = t >> 6, l = t & 63;
    const int fm = l & 15, fq = l >> 4;
    const int lrow = l >> 2;            // 0..15 (rows per 1KB DMA issue)
    const int lcol = (l & 3) << 3;      // 8 bf16 = 16B per lane

    // wave 0 stages the A tiles (hi+lo), wave 1 stages the B tiles
    const ushort* gh = w ? Bh : Ah;
    const ushort* gl = w ? Bl : Al;
    const int r0 = w ? col0 : row0;
    const ushort* ghp = gh + (size_t)(r0 + lrow) * NN + kb + lcol;
    const ushort* glp = gl + (size_t)(r0 + lrow) * NN + kb + lcol;

    floatx4 acc[4][2];
    #pragma unroll
    for (int mi = 0; mi < 4; ++mi) {
        acc[mi][0] = (floatx4)0.f;
        acc[mi][1] = (floatx4)0.f;
    }

    // stage k-step kt (4 tiles, 8 DMA issues per wave) into buffer bufi
    auto STAGE = [&](int bufi, int kt) {
        const int koff = kt << 5;
        ushort* sb = lds + (bufi << 13) + (w << 12);   // this wave's 2 tiles
        #pragma unroll
        for (int rb = 0; rb < 4; ++rb) {               // 16 rows per issue
            gload16(ghp + (size_t)(rb << 4) * NN + koff, sb + (rb << 9));
            gload16(glp + (size_t)(rb << 4) * NN + koff, sb + 2048 + (rb << 9));
        }
    };

    // 24 MFMAs on buffer bufi: acc += Ah*Bh + Al*Bh + Ah*Bl
    auto COMPUTE = [&](int bufi) {
        const ushort* Ash = lds + (bufi << 13);
        const ushort* Asl = Ash + 2048;
        const ushort* Bsh = Ash + 4096;
        const ushort* Bsl = Ash + 6144;
        const int bo = ((w << 5) + fm) * 32 + (fq << 3);
        short8 bh0 = *(const short8*)&Bsh[bo];
        short8 bh1 = *(const short8*)&Bsh[bo + 512];
        short8 bl0 = *(const short8*)&Bsl[bo];
        short8 bl1 = *(const short8*)&Bsl[bo + 512];
        #pragma unroll
        for (int mi = 0; mi < 4; ++mi) {
            const int ao = ((mi << 4) + fm) * 32 + (fq << 3);
            short8 ah = *(const short8*)&Ash[ao];
            short8 al = *(const short8*)&Asl[ao];
            acc[mi][0] = __builtin_amdgcn_mfma_f32_16x16x32_bf16(ah, bh0, acc[mi][0], 0, 0, 0);
            acc[mi][1] = __builtin_amdgcn_mfma_f32_16x16x32_bf16(ah, bh1, acc[mi][1], 0, 0, 0);
            acc[mi][0] = __builtin_amdgcn_mfma_f32_16x16x32_bf16(al, bh0, acc[mi][0], 0, 0, 0);
            acc[mi][1] = __builtin_amdgcn_mfma_f32_16x16x32_bf16(al, bh1, acc[mi][1], 0, 0, 0);
            acc[mi][0] = __builtin_amdgcn_mfma_f32_16x16x32_bf16(ah, bl0, acc[mi][0], 0, 0, 0);
            acc[mi][1] = __builtin_amdgcn_mfma_f32_16x16x32_bf16(ah, bl1, acc[mi][1], 0, 0, 0);
        }
    };

    const int nk = kc >> 5;             // 16 (stage1) or 32 (full K); nk >= 4
    STAGE(0, 0);
    STAGE(1, 1);
    STAGE(2, 2);
    #pragma unroll 1
    for (int kt = 0; kt < nk; ++kt) {
        // wait for stage(kt): keep 2 newer stages (16 loads/wave) in flight
        if (kt + 2 < nk)       asm volatile("s_waitcnt vmcnt(16)" ::: "memory");
        else if (kt + 1 < nk)  asm volatile("s_waitcnt vmcnt(8)"  ::: "memory");
        else                   asm volatile("s_waitcnt vmcnt(0)"  ::: "memory");
        __builtin_amdgcn_s_barrier();            // raw barrier: no vmcnt(0) drain
        __builtin_amdgcn_sched_barrier(0);       // pin: nothing hoists above
        if (kt + 3 < nk) STAGE((kt + 3) & 3, kt + 3);  // into buf (kt-1)%4, free
        COMPUTE(kt & 3);
    }

    // epilogue: C/D layout col=lane&15, row=(lane>>4)*4+reg (m89-verified)
    #pragma unroll
    for (int mi = 0; mi < 4; ++mi) {
        #pragma unroll
        for (int r = 0; r < 4; ++r) {
            int row = row0 + (mi << 4) + (fq << 2) + r;
            #pragma unroll
            for (int ni = 0; ni < 2; ++ni) {
                int col = col0 + (w << 5) + (ni << 4) + fm;
                float v = acc[mi][ni][r];
                size_t idx = (size_t)row * NN + col;
                if (Cf) {
                    Cf[idx] = v;
                } else {
                    ushort h = f2bf(v);
                    Chi[idx] = h;
                    Clo[idx] = f2bf(v - bf2f(h));
                }
            }
        }
    }
}

// stage-1: Mp[z] = partial (Z*Y) over half the K range (fp32 partials, no atomics)
__global__ __launch_bounds__(128) void k_stage1(const ushort* __restrict__ Zh,
                                                const ushort* __restrict__ Zl,
                                                const ushort* __restrict__ Yh,
                                                const ushort* __restrict__ Yl,
                                                float* __restrict__ Mp) {
    int s = blockIdx.z;
    mm_dev(Zh, Zl, Yh, Yl, blockIdx.y * 64, blockIdx.x * 64,
           s * (NN / 2), NN / 2, Mp + (size_t)s * NN * NN, nullptr, nullptr);
}

// stage-2: z=0: Yn = Y*W ; z=1: Zn = W*Z  (epilogue writes bf16 hi/lo directly)
__global__ __launch_bounds__(128) void k_stage2(const ushort* __restrict__ Yh,
                                                const ushort* __restrict__ Yl,
                                                const ushort* __restrict__ Wh,
                                                const ushort* __restrict__ Wl,
                                                const ushort* __restrict__ Zh,
                                                const ushort* __restrict__ Zl,
                                                ushort* __restrict__ Ynh,
                                                ushort* __restrict__ Ynl,
                                                ushort* __restrict__ Znh,
                                                ushort* __restrict__ Znl) {
    if (blockIdx.z == 0)
        mm_dev(Yh, Yl, Wh, Wl, blockIdx.y * 64, blockIdx.x * 64, 0, NN,
               nullptr, Ynh, Ynl);
    else
        mm_dev(Wh, Wl, Zh, Zl, blockIdx.y * 64, blockIdx.x * 64, 0, NN,
               nullptr, Znh, Znl);
}

// final: Yf = Y*W in fp32
__global__ __launch_bounds__(128) void k_final(const ushort* __restrict__ Yh,
                                               const ushort* __restrict__ Yl,
                                               const ushort* __restrict__ Wh,
                                               const ushort* __restrict__ Wl,
                                               float* __restrict__ Yf) {
    mm_dev(Yh, Yl, Wh, Wl, blockIdx.y * 64, blockIdx.x * 64, 0, NN,
           Yf, nullptr, nullptr);
}

// W = 1.5I - 0.25*(Mp0+Mp1+Mp0^T+Mp1^T) -> bf16 hi/lo  (symmetrized M)
__global__ __launch_bounds__(256) void k_wsplit(const float* __restrict__ Mp,
                                                ushort* __restrict__ Wh,
                                                ushort* __restrict__ Wl) {
    int i = blockIdx.x * 256 + threadIdx.x;     // float4 index over NN*NN/4
    int row = i >> 8, c0 = (i & 255) << 2;
    float4 m0 = ((const float4*)Mp)[i];
    float4 m1 = ((const float4*)Mp)[i + NN * NN / 4];
    float mr[4] = {m0.x + m1.x, m0.y + m1.y, m0.z + m1.z, m0.w + m1.w};
    float wv[4];
    #pragma unroll
    for (int j = 0; j < 4; ++j) {
        float mt = Mp[(size_t)(c0 + j) * NN + row] +
                   Mp[(size_t)(c0 + j) * NN + row + (size_t)NN * NN];
        wv[j] = -0.25f * (mr[j] + mt);
    }
    int dd = row - c0;
    if (dd >= 0 && dd < 4) wv[dd] += 1.5f;
    ushort4 hv, lv;
    ushort* hp = (ushort*)&hv; ushort* lp = (ushort*)&lv;
    #pragma unroll
    for (int j = 0; j < 4; ++j) {
        ushort h = f2bf(wv[j]); hp[j] = h; lp[j] = f2bf(wv[j] - bf2f(h));
    }
    *(ushort4*)&Wh[(size_t)i << 2] = hv;
    *(ushort4*)&Wl[(size_t)i << 2] = lv;
}

// iter0: Y0 = D/c -> split ; W0 = 1.5I - 0.5*Y0 -> split
__global__ __launch_bounds__(256) void k_wsplit0(const float* __restrict__ D,
                                                 const float* __restrict__ sc,
                                                 ushort* __restrict__ Yh,
                                                 ushort* __restrict__ Yl,
                                                 ushort* __restrict__ Wh,
                                                 ushort* __restrict__ Wl) {
    int i = blockIdx.x * 256 + threadIdx.x;
    int row = i >> 8, c0 = (i & 255) << 2;
    float invc = sc[1];
    float4 d = ((const float4*)D)[i];
    float yv[4] = {d.x * invc, d.y * invc, d.z * invc, d.w * invc};
    ushort4 yh, yl, wh, wl;
    ushort* yhp = (ushort*)&yh; ushort* ylp = (ushort*)&yl;
    ushort* whp = (ushort*)&wh; ushort* wlp = (ushort*)&wl;
    int dd = row - c0;
    #pragma unroll
    for (int j = 0; j < 4; ++j) {
        float y = yv[j];
        ushort h = f2bf(y); yhp[j] = h; ylp[j] = f2bf(y - bf2f(h));
        float wv = ((dd == j) ? 1.5f : 0.f) - 0.5f * y;
        ushort h2 = f2bf(wv); whp[j] = h2; wlp[j] = f2bf(wv - bf2f(h2));
    }
    *(ushort4*)&Yh[(size_t)i << 2] = yh;
    *(ushort4*)&Yl[(size_t)i << 2] = yl;
    *(ushort4*)&Wh[(size_t)i << 2] = wh;
    *(ushort4*)&Wl[(size_t)i << 2] = wl;
}

// out0[b][n][m] = d_b[n]*d_b[m] + |P_u[n,m]| + 0.01*Q_k[n,m]^2 ; d_b = x[0,:]-x[b,:]
__global__ __launch_bounds__(256) void out0_kernel(const float* __restrict__ x,
                                                   const float* __restrict__ pu,
                                                   const float* __restrict__ qk,
                                                   float* __restrict__ out) {
    int i = blockIdx.x * blockDim.x + threadIdx.x;  // over BB*NN*NN/4
    int rem = i & (NN * NN / 4 - 1);
    int b = i >> 18;
    int n = rem >> 8;
    int m4 = (rem & 255) << 2;
    float dn = x[n] - x[b * NN + n];
    float4 x0v = *(const float4*)(x + m4);
    float4 xbv = *(const float4*)(x + b * NN + m4);
    float4 pv = ((const float4*)pu)[rem];
    float4 qv = ((const float4*)qk)[rem];
    float4 o;
    o.x = dn * (x0v.x - xbv.x) + fabsf(pv.x) + 0.01f * qv.x * qv.x;
    o.y = dn * (x0v.y - xbv.y) + fabsf(pv.y) + 0.01f * qv.y * qv.y;
    o.z = dn * (x0v.z - xbv.z) + fabsf(pv.z) + 0.01f * qv.z * qv.z;
    o.w = dn * (x0v.w - xbv.w) + fabsf(pv.w) + 0.01f * qv.w * qv.w;
    ((float4*)out)[i] = o;
}

// fused sym + out1: p[j][i] = 0.5*sqrt(c)*(Yf[j][i]+Yf[i][j]) + sqrt(N*lam)*v[j]*v[i]
// out1[0][b][j][i] = x[b][i] + p ; out1[0][b][N+j][i] = x[b][i] - p
__global__ __launch_bounds__(256) void k_out1(const float* __restrict__ x,
                                              const float* __restrict__ Yf,
                                              const float* __restrict__ sc,
                                              const float* __restrict__ v,
                                              float* __restrict__ out1) {
    int i = blockIdx.x * 256 + threadIdx.x;     // over NN*NN/4
    int j = i >> 8, i0 = (i & 255) << 2;
    float s = 0.5f * sc[2], s1v = sc[4] * v[j];
    float4 yr = *(const float4*)(Yf + (size_t)j * NN + i0);
    float yc0 = Yf[(size_t)(i0 + 0) * NN + j];
    float yc1 = Yf[(size_t)(i0 + 1) * NN + j];
    float yc2 = Yf[(size_t)(i0 + 2) * NN + j];
    float yc3 = Yf[(size_t)(i0 + 3) * NN + j];
    float4 vc = *(const float4*)(v + i0);
    float4 p;
    p.x = s * (yr.x + yc0) + s1v * vc.x;
    p.y = s * (yr.y + yc1) + s1v * vc.y;
    p.z = s * (yr.z + yc2) + s1v * vc.z;
    p.w = s * (yr.w + yc3) + s1v * vc.w;
    #pragma unroll
    for (int b = 0; b < BB; ++b) {
        float4 xv = *(const float4*)(x + b * NN + i0);
        float4 a, m;
        a.x = xv.x + p.x; a.y = xv.y + p.y; a.z = xv.z + p.z; a.w = xv.w + p.w;
        m.x = xv.x - p.x; m.y = xv.y - p.y; m.z = xv.z - p.z; m.w = xv.w - p.w;
        float* base = out1 + (size_t)b * 2 * NN * NN;
        *(float4*)(base + (size_t)j * NN + i0) = a;
        *(float4*)(base + (size_t)(NN + j) * NN + i0) = m;
    }
}

extern "C" void kernel_launch(void* const* d_in, const int* in_sizes, int n_in,
                              void* d_out, int out_size, void* d_ws, size_t ws_size,
                              hipStream_t stream) {
    const float* x  = (const float*)d_in[0];
    const float* pu = (const float*)d_in[1];
    const float* qk = (const float*)d_in[2];
    float* out = (float*)d_out;
    char* ws = (char*)d_ws;

    // layout: [0,8MB) fp32 Mp0/Mp1 (Mp0 doubles as D before iter1 and Yf after
    // last wsplit); [8MB,28MB) five bf16 hi/lo pairs (4MB each); vectors after.
    float* Mp = (float*)ws;
    float* D  = Mp;
    float* Yf = Mp;
    ushort* hi[5]; ushort* lo[5];
    for (int k = 0; k < 5; ++k) {
        hi[k] = (ushort*)(ws + (size_t)8 * MB + (size_t)k * 4 * MB);
        lo[k] = (ushort*)(ws + (size_t)8 * MB + (size_t)k * 4 * MB + 2 * MB);
    }
    float* vv = (float*)(ws + (size_t)28 * MB);
    float* vw = (float*)(ws + (size_t)28 * MB + 4096);
    float* vt = (float*)(ws + (size_t)28 * MB + 8192);
    float* sc = (float*)(ws + (size_t)28 * MB + 12288);

    // ---- deflation: top eigpair of |P_u| via 3 matvecs ----
    hipMemsetAsync(sc, 0, 64, stream);
    matvec_abs<<<NN, 256, 0, stream>>>(pu, vv, vt, 1);
    norm_vec<<<1, 256, 0, stream>>>(vt, vv);
    matvec_abs<<<NN, 256, 0, stream>>>(pu, vv, vt, 0);
    norm_vec<<<1, 256, 0, stream>>>(vt, vv);
    matvec_abs<<<NN, 256, 0, stream>>>(pu, vv, vw, 0);
    dot_vec<<<1, 256, 0, stream>>>(vv, vw, sc + 5);
    deflate_kernel<<<NN * NN / 4 / 256, 256, 0, stream>>>(pu, vv, vw, sc, D);
    finalize_kernel<<<1, 1, 0, stream>>>(sc);

    // ---- iter 0: Y0,W0 from D; Y1 = Y0*W0 ; Z1 = W0 (pointer swap) ----
    k_wsplit0<<<NN * NN / 4 / 256, 256, 0, stream>>>(D, sc, hi[0], lo[0], hi[1], lo[1]);
    k_stage2<<<dim3(16, 16, 1), 128, 0, stream>>>(hi[0], lo[0], hi[1], lo[1],
                                                  hi[0], lo[0],   // Z unused (z=0 only)
                                                  hi[2], lo[2], hi[3], lo[3]);
    int Y = 2, Z = 1, f0 = 0, f1 = 3, f2 = 4;

    // ---- iters 1..NS_ITERS-1 ----
    for (int it = 1; it < NS_ITERS; ++it) {
        int W = f0;
        k_stage1<<<dim3(16, 16, 2), 128, 0, stream>>>(hi[Z], lo[Z], hi[Y], lo[Y], Mp);
        k_wsplit<<<NN * NN / 4 / 256, 256, 0, stream>>>(Mp, hi[W], lo[W]);
        if (it + 1 < NS_ITERS) {
            int Yn = f1, Zn = f2;
            k_stage2<<<dim3(16, 16, 2), 128, 0, stream>>>(
                hi[Y], lo[Y], hi[W], lo[W], hi[Z], lo[Z],
                hi[Yn], lo[Yn], hi[Zn], lo[Zn]);
            f0 = Y; f1 = Z; f2 = W;
            Y = Yn; Z = Zn;
        } else {
            k_final<<<dim3(16, 16, 1), 128, 0, stream>>>(hi[Y], lo[Y], hi[W], lo[W], Yf);
        }
    }

    // ---- outputs ----
    out0_kernel<<<(BB * NN * NN / 4) / 256, 256, 0, stream>>>(x, pu, qk, out);
    k_out1<<<NN * NN / 4 / 256, 256, 0, stream>>>(x, Yf, sc, vv,
                                                  out + (size_t)BB * NN * NN);
}

// Round 6
// 573.165 us; speedup vs baseline: 1.3960x; 1.1271x over previous
//
#include <hip/hip_runtime.h>
#include <math.h>

#define NN 1024
#define BB 8
#define NS_ITERS 10
#define EPS_SHIFT 4.0f
#define MB (1u<<20)

typedef __attribute__((ext_vector_type(8))) short short8;
typedef __attribute__((ext_vector_type(4))) float floatx4;

__device__ __forceinline__ ushort f2bf(float f) {
    union { float f; uint32_t u; } v; v.f = f;
    uint32_t u = v.u;
    uint32_t r = (u + 0x7fffu + ((u >> 16) & 1u)) >> 16;
    return (ushort)r;
}
__device__ __forceinline__ float bf2f(ushort h) {
    union { uint32_t u; float f; } v; v.u = ((uint32_t)h) << 16;
    return v.f;
}

// async global->LDS, 16B per lane (dest = wave-uniform base + lane*16)
__device__ __forceinline__ void gload16(const ushort* g, ushort* s) {
    __builtin_amdgcn_global_load_lds(
        (__attribute__((address_space(1))) unsigned int*)(g),
        (__attribute__((address_space(3))) unsigned int*)(s), 16, 0, 0);
}

// ---------- block reduction helper (result valid on thread 0) ----------
__device__ __forceinline__ float block_sum(float v) {
    #pragma unroll
    for (int off = 32; off > 0; off >>= 1) v += __shfl_down(v, off, 64);
    __shared__ float red[4];
    int lane = threadIdx.x & 63, wid = threadIdx.x >> 6;
    if (lane == 0) red[wid] = v;
    __syncthreads();
    float t = 0.f;
    if (threadIdx.x == 0) t = red[0] + red[1] + red[2] + red[3];
    return t;
}

// ---------- power iteration pieces: y[row] = sum_j |pu[row][j]| * x[j] ----------
__global__ __launch_bounds__(256) void matvec_abs(const float* __restrict__ pu,
                                                  const float* __restrict__ x,
                                                  float* __restrict__ y,
                                                  int use_ones) {
    int row = blockIdx.x;
    const float4* pr = (const float4*)(pu + (size_t)row * NN);
    float4 p = pr[threadIdx.x];
    float s;
    if (use_ones) {
        s = fabsf(p.x) + fabsf(p.y) + fabsf(p.z) + fabsf(p.w);
    } else {
        float4 xx = ((const float4*)x)[threadIdx.x];
        s = fabsf(p.x) * xx.x + fabsf(p.y) * xx.y + fabsf(p.z) * xx.z + fabsf(p.w) * xx.w;
    }
    s = block_sum(s);
    if (threadIdx.x == 0) y[row] = s;
}

__global__ void norm_vec(const float* __restrict__ y, float* __restrict__ v) {
    float ss = 0.f;
    for (int i = threadIdx.x; i < NN; i += 256) { float t = y[i]; ss += t * t; }
    #pragma unroll
    for (int off = 32; off > 0; off >>= 1) ss += __shfl_down(ss, off, 64);
    __shared__ float red[4];
    __shared__ float s_inv;
    int lane = threadIdx.x & 63, wid = threadIdx.x >> 6;
    if (lane == 0) red[wid] = ss;
    __syncthreads();
    if (threadIdx.x == 0) s_inv = rsqrtf(red[0] + red[1] + red[2] + red[3]);
    __syncthreads();
    float inv = s_inv;
    for (int i = threadIdx.x; i < NN; i += 256) v[i] = y[i] * inv;
}

__global__ void dot_vec(const float* __restrict__ a, const float* __restrict__ b,
                        float* __restrict__ out) {
    float s = 0.f;
    for (int i = threadIdx.x; i < NN; i += 256) s += a[i] * b[i];
    s = block_sum(s);
    if (threadIdx.x == 0) out[0] = s;
}

// ---------- deflation: D = N*(|pu| - v w^T - w v^T + lam v v^T) + eps*I ----------
__global__ __launch_bounds__(256) void deflate_kernel(const float* __restrict__ pu,
                                                      const float* __restrict__ v,
                                                      const float* __restrict__ w,
                                                      float* __restrict__ sc,
                                                      float* __restrict__ D) {
    int idx = blockIdx.x * 256 + threadIdx.x;   // over NN*NN/4
    int row = idx >> 8;
    int c0 = (idx & 255) << 2;
    float lam = sc[5];
    float vr = v[row], wr = w[row];
    float4 p = ((const float4*)pu)[idx];
    float4 vc = *(const float4*)(v + c0);
    float4 wc = *(const float4*)(w + c0);
    float4 d;
    d.x = (float)NN * (fabsf(p.x) - vr * wc.x - wr * vc.x + lam * vr * vc.x);
    d.y = (float)NN * (fabsf(p.y) - vr * wc.y - wr * vc.y + lam * vr * vc.y);
    d.z = (float)NN * (fabsf(p.z) - vr * wc.z - wr * vc.z + lam * vr * vc.z);
    d.w = (float)NN * (fabsf(p.w) - vr * wc.w - wr * vc.w + lam * vr * vc.w);
    int dd = row - c0;
    if (dd == 0) d.x += EPS_SHIFT;
    else if (dd == 1) d.y += EPS_SHIFT;
    else if (dd == 2) d.z += EPS_SHIFT;
    else if (dd == 3) d.w += EPS_SHIFT;
    ((float4*)D)[idx] = d;
    float ss = d.x * d.x + d.y * d.y + d.z * d.z + d.w * d.w;
    ss = block_sum(ss);
    if (threadIdx.x == 0) atomicAdd(sc, ss);
}

// sc[0]=||D||_F^2, sc[5]=lam~  ->  sc[1]=1/c, sc[2]=sqrt(c), sc[4]=sqrt(N*lam~)
__global__ void finalize_kernel(float* sc) {
    float c = sqrtf(sc[0]);
    sc[1] = 1.f / c;
    sc[2] = sqrtf(c);
    sc[4] = sqrtf((float)NN * sc[5]);
}

// ---------- MFMA GEMM: 64x64 tile, 128 threads (2 waves), split-bf16 fp32 ----------
// R5 schedule (counted vmcnt, 4 buffers, depth-3 prefetch, raw barrier).
// NEW: optional CfT output — the fp32 tile is also emitted TRANSPOSED via an
// LDS round-trip (stride-68 padded layout, coalesced float4 stores), so the
// transposed consumers (k_wsplit, k_out1) never do 4KB-stride scalar reads
// (16x cacheline overfetch through cross-XCD L3 — the R6 theory).
__device__ __forceinline__ void mm_dev(const ushort* __restrict__ Ah,
                                       const ushort* __restrict__ Al,
                                       const ushort* __restrict__ Bh,
                                       const ushort* __restrict__ Bl,
                                       int row0, int col0, int kb, int kc,
                                       float* __restrict__ Cf,
                                       float* __restrict__ CfT,
                                       ushort* __restrict__ Chi,
                                       ushort* __restrict__ Clo) {
    // 4 buffers x 4 tiles (Ah,Al,Bh,Bl) x 64x32 bf16 = 64 KiB
    __shared__ __align__(16) ushort lds[4 * 4 * 2048];
    const int t = threadIdx.x;          // 0..127
    const int w = t >> 6, l = t & 63;
    const int fm = l & 15, fq = l >> 4;
    const int lrow = l >> 2;            // 0..15 (rows per 1KB DMA issue)
    const int lcol = (l & 3) << 3;      // 8 bf16 = 16B per lane

    // wave 0 stages the A tiles (hi+lo), wave 1 stages the B tiles
    const ushort* gh = w ? Bh : Ah;
    const ushort* gl = w ? Bl : Al;
    const int r0 = w ? col0 : row0;
    const ushort* ghp = gh + (size_t)(r0 + lrow) * NN + kb + lcol;
    const ushort* glp = gl + (size_t)(r0 + lrow) * NN + kb + lcol;

    floatx4 acc[4][2];
    #pragma unroll
    for (int mi = 0; mi < 4; ++mi) {
        acc[mi][0] = (floatx4)0.f;
        acc[mi][1] = (floatx4)0.f;
    }

    // stage k-step kt (4 tiles, 8 DMA issues per wave) into buffer bufi
    auto STAGE = [&](int bufi, int kt) {
        const int koff = kt << 5;
        ushort* sb = lds + (bufi << 13) + (w << 12);   // this wave's 2 tiles
        #pragma unroll
        for (int rb = 0; rb < 4; ++rb) {               // 16 rows per issue
            gload16(ghp + (size_t)(rb << 4) * NN + koff, sb + (rb << 9));
            gload16(glp + (size_t)(rb << 4) * NN + koff, sb + 2048 + (rb << 9));
        }
    };

    // 24 MFMAs on buffer bufi: acc += Ah*Bh + Al*Bh + Ah*Bl
    auto COMPUTE = [&](int bufi) {
        const ushort* Ash = lds + (bufi << 13);
        const ushort* Asl = Ash + 2048;
        const ushort* Bsh = Ash + 4096;
        const ushort* Bsl = Ash + 6144;
        const int bo = ((w << 5) + fm) * 32 + (fq << 3);
        short8 bh0 = *(const short8*)&Bsh[bo];
        short8 bh1 = *(const short8*)&Bsh[bo + 512];
        short8 bl0 = *(const short8*)&Bsl[bo];
        short8 bl1 = *(const short8*)&Bsl[bo + 512];
        #pragma unroll
        for (int mi = 0; mi < 4; ++mi) {
            const int ao = ((mi << 4) + fm) * 32 + (fq << 3);
            short8 ah = *(const short8*)&Ash[ao];
            short8 al = *(const short8*)&Asl[ao];
            acc[mi][0] = __builtin_amdgcn_mfma_f32_16x16x32_bf16(ah, bh0, acc[mi][0], 0, 0, 0);
            acc[mi][1] = __builtin_amdgcn_mfma_f32_16x16x32_bf16(ah, bh1, acc[mi][1], 0, 0, 0);
            acc[mi][0] = __builtin_amdgcn_mfma_f32_16x16x32_bf16(al, bh0, acc[mi][0], 0, 0, 0);
            acc[mi][1] = __builtin_amdgcn_mfma_f32_16x16x32_bf16(al, bh1, acc[mi][1], 0, 0, 0);
            acc[mi][0] = __builtin_amdgcn_mfma_f32_16x16x32_bf16(ah, bl0, acc[mi][0], 0, 0, 0);
            acc[mi][1] = __builtin_amdgcn_mfma_f32_16x16x32_bf16(ah, bl1, acc[mi][1], 0, 0, 0);
        }
    };

    const int nk = kc >> 5;             // 16 (stage1) or 32 (full K); nk >= 4
    STAGE(0, 0);
    STAGE(1, 1);
    STAGE(2, 2);
    #pragma unroll 1
    for (int kt = 0; kt < nk; ++kt) {
        // wait for stage(kt): keep 2 newer stages (16 loads/wave) in flight
        if (kt + 2 < nk)       asm volatile("s_waitcnt vmcnt(16)" ::: "memory");
        else if (kt + 1 < nk)  asm volatile("s_waitcnt vmcnt(8)"  ::: "memory");
        else                   asm volatile("s_waitcnt vmcnt(0)"  ::: "memory");
        __builtin_amdgcn_s_barrier();            // raw barrier: no vmcnt(0) drain
        __builtin_amdgcn_sched_barrier(0);       // pin: nothing hoists above
        if (kt + 3 < nk) STAGE((kt + 3) & 3, kt + 3);  // into buf (kt-1)%4, free
        COMPUTE(kt & 3);
    }

    // epilogue: C/D layout col=lane&15, row=(lane>>4)*4+reg (m89-verified)
    #pragma unroll
    for (int mi = 0; mi < 4; ++mi) {
        #pragma unroll
        for (int r = 0; r < 4; ++r) {
            int row = row0 + (mi << 4) + (fq << 2) + r;
            #pragma unroll
            for (int ni = 0; ni < 2; ++ni) {
                int col = col0 + (w << 5) + (ni << 4) + fm;
                float v = acc[mi][ni][r];
                size_t idx = (size_t)row * NN + col;
                if (Cf) {
                    Cf[idx] = v;
                } else {
                    ushort h = f2bf(v);
                    Chi[idx] = h;
                    Clo[idx] = f2bf(v - bf2f(h));
                }
            }
        }
    }

    // transposed emit: LDS round-trip, coalesced float4 stores of C^T
    if (CfT) {
        __syncthreads();                 // all waves done with k-loop LDS
        float* lf = (float*)lds;         // [64 cols][stride 68] fp32 = 17.4KB
        #pragma unroll
        for (int mi = 0; mi < 4; ++mi) {
            #pragma unroll
            for (int r = 0; r < 4; ++r) {
                int rl = (mi << 4) + (fq << 2) + r;
                #pragma unroll
                for (int ni = 0; ni < 2; ++ni) {
                    int cl = (w << 5) + (ni << 4) + fm;
                    lf[cl * 68 + rl] = acc[mi][ni][r];
                }
            }
        }
        __syncthreads();
        int c = t >> 1, half = t & 1;
        const float* src = lf + c * 68 + (half << 5);
        float* dst = CfT + (size_t)(col0 + c) * NN + row0 + (half << 5);
        #pragma unroll
        for (int j = 0; j < 8; ++j)
            *(float4*)(dst + (j << 2)) = *(const float4*)(src + (j << 2));
    }
}

// stage-1: Mp[z] = partial (Z*Y) over half the K range; also writes Mp[z]^T
__global__ __launch_bounds__(128) void k_stage1(const ushort* __restrict__ Zh,
                                                const ushort* __restrict__ Zl,
                                                const ushort* __restrict__ Yh,
                                                const ushort* __restrict__ Yl,
                                                float* __restrict__ Mp,
                                                float* __restrict__ MpT0,
                                                float* __restrict__ MpT1) {
    int s = blockIdx.z;
    mm_dev(Zh, Zl, Yh, Yl, blockIdx.y * 64, blockIdx.x * 64,
           s * (NN / 2), NN / 2, Mp + (size_t)s * NN * NN,
           s ? MpT1 : MpT0, nullptr, nullptr);
}

// stage-2: z=0: Yn = Y*W ; z=1: Zn = W*Z  (epilogue writes bf16 hi/lo directly)
__global__ __launch_bounds__(128) void k_stage2(const ushort* __restrict__ Yh,
                                                const ushort* __restrict__ Yl,
                                                const ushort* __restrict__ Wh,
                                                const ushort* __restrict__ Wl,
                                                const ushort* __restrict__ Zh,
                                                const ushort* __restrict__ Zl,
                                                ushort* __restrict__ Ynh,
                                                ushort* __restrict__ Ynl,
                                                ushort* __restrict__ Znh,
                                                ushort* __restrict__ Znl) {
    if (blockIdx.z == 0)
        mm_dev(Yh, Yl, Wh, Wl, blockIdx.y * 64, blockIdx.x * 64, 0, NN,
               nullptr, nullptr, Ynh, Ynl);
    else
        mm_dev(Wh, Wl, Zh, Zl, blockIdx.y * 64, blockIdx.x * 64, 0, NN,
               nullptr, nullptr, Znh, Znl);
}

// final: Yf = Y*W in fp32 (+ transpose for k_out1)
__global__ __launch_bounds__(128) void k_final(const ushort* __restrict__ Yh,
                                               const ushort* __restrict__ Yl,
                                               const ushort* __restrict__ Wh,
                                               const ushort* __restrict__ Wl,
                                               float* __restrict__ Yf,
                                               float* __restrict__ YfT) {
    mm_dev(Yh, Yl, Wh, Wl, blockIdx.y * 64, blockIdx.x * 64, 0, NN,
           Yf, YfT, nullptr, nullptr);
}

// W = 1.5I - 0.25*(Mp0+Mp1+Mp0^T+Mp1^T) -> bf16 hi/lo  (all reads coalesced)
__global__ __launch_bounds__(256) void k_wsplit(const float* __restrict__ Mp,
                                                const float* __restrict__ MpT0,
                                                const float* __restrict__ MpT1,
                                                ushort* __restrict__ Wh,
                                                ushort* __restrict__ Wl) {
    int i = blockIdx.x * 256 + threadIdx.x;     // float4 index over NN*NN/4
    int row = i >> 8, c0 = (i & 255) << 2;
    float4 m0 = ((const float4*)Mp)[i];
    float4 m1 = ((const float4*)Mp)[i + NN * NN / 4];
    float4 t0 = ((const float4*)MpT0)[i];
    float4 t1 = ((const float4*)MpT1)[i];
    float wv[4] = {-0.25f * (m0.x + m1.x + t0.x + t1.x),
                   -0.25f * (m0.y + m1.y + t0.y + t1.y),
                   -0.25f * (m0.z + m1.z + t0.z + t1.z),
                   -0.25f * (m0.w + m1.w + t0.w + t1.w)};
    int dd = row - c0;
    if (dd >= 0 && dd < 4) wv[dd] += 1.5f;
    ushort4 hv, lv;
    ushort* hp = (ushort*)&hv; ushort* lp = (ushort*)&lv;
    #pragma unroll
    for (int j = 0; j < 4; ++j) {
        ushort h = f2bf(wv[j]); hp[j] = h; lp[j] = f2bf(wv[j] - bf2f(h));
    }
    *(ushort4*)&Wh[(size_t)i << 2] = hv;
    *(ushort4*)&Wl[(size_t)i << 2] = lv;
}

// iter0: Y0 = D/c -> split ; W0 = 1.5I - 0.5*Y0 -> split
__global__ __launch_bounds__(256) void k_wsplit0(const float* __restrict__ D,
                                                 const float* __restrict__ sc,
                                                 ushort* __restrict__ Yh,
                                                 ushort* __restrict__ Yl,
                                                 ushort* __restrict__ Wh,
                                                 ushort* __restrict__ Wl) {
    int i = blockIdx.x * 256 + threadIdx.x;
    int row = i >> 8, c0 = (i & 255) << 2;
    float invc = sc[1];
    float4 d = ((const float4*)D)[i];
    float yv[4] = {d.x * invc, d.y * invc, d.z * invc, d.w * invc};
    ushort4 yh, yl, wh, wl;
    ushort* yhp = (ushort*)&yh; ushort* ylp = (ushort*)&yl;
    ushort* whp = (ushort*)&wh; ushort* wlp = (ushort*)&wl;
    int dd = row - c0;
    #pragma unroll
    for (int j = 0; j < 4; ++j) {
        float y = yv[j];
        ushort h = f2bf(y); yhp[j] = h; ylp[j] = f2bf(y - bf2f(h));
        float wv = ((dd == j) ? 1.5f : 0.f) - 0.5f * y;
        ushort h2 = f2bf(wv); whp[j] = h2; wlp[j] = f2bf(wv - bf2f(h2));
    }
    *(ushort4*)&Yh[(size_t)i << 2] = yh;
    *(ushort4*)&Yl[(size_t)i << 2] = yl;
    *(ushort4*)&Wh[(size_t)i << 2] = wh;
    *(ushort4*)&Wl[(size_t)i << 2] = wl;
}

// out0[b][n][m] = d_b[n]*d_b[m] + |P_u[n,m]| + 0.01*Q_k[n,m]^2 ; d_b = x[0,:]-x[b,:]
__global__ __launch_bounds__(256) void out0_kernel(const float* __restrict__ x,
                                                   const float* __restrict__ pu,
                                                   const float* __restrict__ qk,
                                                   float* __restrict__ out) {
    int i = blockIdx.x * blockDim.x + threadIdx.x;  // over BB*NN*NN/4
    int rem = i & (NN * NN / 4 - 1);
    int b = i >> 18;
    int n = rem >> 8;
    int m4 = (rem & 255) << 2;
    float dn = x[n] - x[b * NN + n];
    float4 x0v = *(const float4*)(x + m4);
    float4 xbv = *(const float4*)(x + b * NN + m4);
    float4 pv = ((const float4*)pu)[rem];
    float4 qv = ((const float4*)qk)[rem];
    float4 o;
    o.x = dn * (x0v.x - xbv.x) + fabsf(pv.x) + 0.01f * qv.x * qv.x;
    o.y = dn * (x0v.y - xbv.y) + fabsf(pv.y) + 0.01f * qv.y * qv.y;
    o.z = dn * (x0v.z - xbv.z) + fabsf(pv.z) + 0.01f * qv.z * qv.z;
    o.w = dn * (x0v.w - xbv.w) + fabsf(pv.w) + 0.01f * qv.w * qv.w;
    ((float4*)out)[i] = o;
}

// fused sym + out1: p[j][i] = 0.5*sqrt(c)*(Yf[j][i]+YfT[j][i]) + sqrt(N*lam)*v[j]*v[i]
// out1[0][b][j][i] = x[b][i] + p ; out1[0][b][N+j][i] = x[b][i] - p
__global__ __launch_bounds__(256) void k_out1(const float* __restrict__ x,
                                              const float* __restrict__ Yf,
                                              const float* __restrict__ YfT,
                                              const float* __restrict__ sc,
                                              const float* __restrict__ v,
                                              float* __restrict__ out1) {
    int i = blockIdx.x * 256 + threadIdx.x;     // over NN*NN/4
    int j = i >> 8, i0 = (i & 255) << 2;
    float s = 0.5f * sc[2], s1v = sc[4] * v[j];
    float4 yr = *(const float4*)(Yf + (size_t)j * NN + i0);
    float4 yc = *(const float4*)(YfT + (size_t)j * NN + i0);
    float4 vc = *(const float4*)(v + i0);
    float4 p;
    p.x = s * (yr.x + yc.x) + s1v * vc.x;
    p.y = s * (yr.y + yc.y) + s1v * vc.y;
    p.z = s * (yr.z + yc.z) + s1v * vc.z;
    p.w = s * (yr.w + yc.w) + s1v * vc.w;
    #pragma unroll
    for (int b = 0; b < BB; ++b) {
        float4 xv = *(const float4*)(x + b * NN + i0);
        float4 a, m;
        a.x = xv.x + p.x; a.y = xv.y + p.y; a.z = xv.z + p.z; a.w = xv.w + p.w;
        m.x = xv.x - p.x; m.y = xv.y - p.y; m.z = xv.z - p.z; m.w = xv.w - p.w;
        float* base = out1 + (size_t)b * 2 * NN * NN;
        *(float4*)(base + (size_t)j * NN + i0) = a;
        *(float4*)(base + (size_t)(NN + j) * NN + i0) = m;
    }
}

extern "C" void kernel_launch(void* const* d_in, const int* in_sizes, int n_in,
                              void* d_out, int out_size, void* d_ws, size_t ws_size,
                              hipStream_t stream) {
    const float* x  = (const float*)d_in[0];
    const float* pu = (const float*)d_in[1];
    const float* qk = (const float*)d_in[2];
    float* out = (float*)d_out;
    char* ws = (char*)d_ws;

    // layout: [0,8MB) fp32 Mp0/Mp1 (Mp0 doubles as D before iter1 and Yf after
    // last wsplit; Mp1 doubles as YfT after the last wsplit);
    // [8MB,28MB) five bf16 hi/lo pairs (4MB each); vectors after.
    float* Mp = (float*)ws;
    float* D  = Mp;
    float* Yf = Mp;
    float* YfT = (float*)(ws + (size_t)4 * MB);
    ushort* hi[5]; ushort* lo[5];
    for (int k = 0; k < 5; ++k) {
        hi[k] = (ushort*)(ws + (size_t)8 * MB + (size_t)k * 4 * MB);
        lo[k] = (ushort*)(ws + (size_t)8 * MB + (size_t)k * 4 * MB + 2 * MB);
    }
    float* vv = (float*)(ws + (size_t)28 * MB);
    float* vw = (float*)(ws + (size_t)28 * MB + 4096);
    float* vt = (float*)(ws + (size_t)28 * MB + 8192);
    float* sc = (float*)(ws + (size_t)28 * MB + 12288);

    // ---- deflation: top eigpair of |P_u| via 3 matvecs ----
    hipMemsetAsync(sc, 0, 64, stream);
    matvec_abs<<<NN, 256, 0, stream>>>(pu, vv, vt, 1);
    norm_vec<<<1, 256, 0, stream>>>(vt, vv);
    matvec_abs<<<NN, 256, 0, stream>>>(pu, vv, vt, 0);
    norm_vec<<<1, 256, 0, stream>>>(vt, vv);
    matvec_abs<<<NN, 256, 0, stream>>>(pu, vv, vw, 0);
    dot_vec<<<1, 256, 0, stream>>>(vv, vw, sc + 5);
    deflate_kernel<<<NN * NN / 4 / 256, 256, 0, stream>>>(pu, vv, vw, sc, D);
    finalize_kernel<<<1, 1, 0, stream>>>(sc);

    // ---- iter 0: Y0,W0 from D; Y1 = Y0*W0 ; Z1 = W0 (pointer swap) ----
    k_wsplit0<<<NN * NN / 4 / 256, 256, 0, stream>>>(D, sc, hi[0], lo[0], hi[1], lo[1]);
    k_stage2<<<dim3(16, 16, 1), 128, 0, stream>>>(hi[0], lo[0], hi[1], lo[1],
                                                  hi[0], lo[0],   // Z unused (z=0 only)
                                                  hi[2], lo[2], hi[3], lo[3]);
    int Y = 2, Z = 1, f0 = 0, f1 = 3, f2 = 4;

    // ---- iters 1..NS_ITERS-1 ----
    for (int it = 1; it < NS_ITERS; ++it) {
        int W = f0;
        // MpT0/MpT1 scratch: the f1/f2 buffer regions (dead until stage2 writes
        // them, and k_wsplit reads them strictly before that in stream order)
        float* MpT0 = (float*)hi[f1];
        float* MpT1 = (float*)hi[f2];
        k_stage1<<<dim3(16, 16, 2), 128, 0, stream>>>(hi[Z], lo[Z], hi[Y], lo[Y],
                                                      Mp, MpT0, MpT1);
        k_wsplit<<<NN * NN / 4 / 256, 256, 0, stream>>>(Mp, MpT0, MpT1,
                                                        hi[W], lo[W]);
        if (it + 1 < NS_ITERS) {
            int Yn = f1, Zn = f2;
            k_stage2<<<dim3(16, 16, 2), 128, 0, stream>>>(
                hi[Y], lo[Y], hi[W], lo[W], hi[Z], lo[Z],
                hi[Yn], lo[Yn], hi[Zn], lo[Zn]);
            f0 = Y; f1 = Z; f2 = W;
            Y = Yn; Z = Zn;
        } else {
            k_final<<<dim3(16, 16, 1), 128, 0, stream>>>(hi[Y], lo[Y], hi[W], lo[W],
                                                         Yf, YfT);
        }
    }

    // ---- outputs ----
    out0_kernel<<<(BB * NN * NN / 4) / 256, 256, 0, stream>>>(x, pu, qk, out);
    k_out1<<<NN * NN / 4 / 256, 256, 0, stream>>>(x, Yf, YfT, sc, vv,
                                                  out + (size_t)BB * NN * NN);
}

// Round 8
// 567.508 us; speedup vs baseline: 1.4100x; 1.0100x over previous
//
#include <hip/hip_runtime.h>
#include <math.h>

#define NN 1024
#define BB 8
#define NS_ITERS 10
#define EPS_SHIFT 4.0f
#define MB (1u<<20)

typedef __attribute__((ext_vector_type(8))) short short8;
typedef __attribute__((ext_vector_type(4))) float floatx4;

__device__ __forceinline__ ushort f2bf(float f) {
    union { float f; uint32_t u; } v; v.f = f;
    uint32_t u = v.u;
    uint32_t r = (u + 0x7fffu + ((u >> 16) & 1u)) >> 16;
    return (ushort)r;
}
__device__ __forceinline__ float bf2f(ushort h) {
    union { uint32_t u; float f; } v; v.u = ((uint32_t)h) << 16;
    return v.f;
}

// async global->LDS, 16B per lane (dest = wave-uniform base + lane*16)
__device__ __forceinline__ void gload16(const ushort* g, ushort* s) {
    __builtin_amdgcn_global_load_lds(
        (__attribute__((address_space(1))) unsigned int*)(g),
        (__attribute__((address_space(3))) unsigned int*)(s), 16, 0, 0);
}

// ---------- block reduction helper (result valid on thread 0) ----------
__device__ __forceinline__ float block_sum(float v) {
    #pragma unroll
    for (int off = 32; off > 0; off >>= 1) v += __shfl_down(v, off, 64);
    __shared__ float red[4];
    int lane = threadIdx.x & 63, wid = threadIdx.x >> 6;
    if (lane == 0) red[wid] = v;
    __syncthreads();
    float t = 0.f;
    if (threadIdx.x == 0) t = red[0] + red[1] + red[2] + red[3];
    return t;
}

// ---------- power iteration pieces: y[row] = sum_j |pu[row][j]| * x[j] ----------
__global__ __launch_bounds__(256) void matvec_abs(const float* __restrict__ pu,
                                                  const float* __restrict__ x,
                                                  float* __restrict__ y,
                                                  int use_ones) {
    int row = blockIdx.x;
    const float4* pr = (const float4*)(pu + (size_t)row * NN);
    float4 p = pr[threadIdx.x];
    float s;
    if (use_ones) {
        s = fabsf(p.x) + fabsf(p.y) + fabsf(p.z) + fabsf(p.w);
    } else {
        float4 xx = ((const float4*)x)[threadIdx.x];
        s = fabsf(p.x) * xx.x + fabsf(p.y) * xx.y + fabsf(p.z) * xx.z + fabsf(p.w) * xx.w;
    }
    s = block_sum(s);
    if (threadIdx.x == 0) y[row] = s;
}

__global__ void norm_vec(const float* __restrict__ y, float* __restrict__ v) {
    float ss = 0.f;
    for (int i = threadIdx.x; i < NN; i += 256) { float t = y[i]; ss += t * t; }
    #pragma unroll
    for (int off = 32; off > 0; off >>= 1) ss += __shfl_down(ss, off, 64);
    __shared__ float red[4];
    __shared__ float s_inv;
    int lane = threadIdx.x & 63, wid = threadIdx.x >> 6;
    if (lane == 0) red[wid] = ss;
    __syncthreads();
    if (threadIdx.x == 0) s_inv = rsqrtf(red[0] + red[1] + red[2] + red[3]);
    __syncthreads();
    float inv = s_inv;
    for (int i = threadIdx.x; i < NN; i += 256) v[i] = y[i] * inv;
}

__global__ void dot_vec(const float* __restrict__ a, const float* __restrict__ b,
                        float* __restrict__ out) {
    float s = 0.f;
    for (int i = threadIdx.x; i < NN; i += 256) s += a[i] * b[i];
    s = block_sum(s);
    if (threadIdx.x == 0) out[0] = s;
}

// ---------- deflation: D = N*(|pu| - v w^T - w v^T + lam v v^T) + eps*I ----------
__global__ __launch_bounds__(256) void deflate_kernel(const float* __restrict__ pu,
                                                      const float* __restrict__ v,
                                                      const float* __restrict__ w,
                                                      float* __restrict__ sc,
                                                      float* __restrict__ D) {
    int idx = blockIdx.x * 256 + threadIdx.x;   // over NN*NN/4
    int row = idx >> 8;
    int c0 = (idx & 255) << 2;
    float lam = sc[5];
    float vr = v[row], wr = w[row];
    float4 p = ((const float4*)pu)[idx];
    float4 vc = *(const float4*)(v + c0);
    float4 wc = *(const float4*)(w + c0);
    float4 d;
    d.x = (float)NN * (fabsf(p.x) - vr * wc.x - wr * vc.x + lam * vr * vc.x);
    d.y = (float)NN * (fabsf(p.y) - vr * wc.y - wr * vc.y + lam * vr * vc.y);
    d.z = (float)NN * (fabsf(p.z) - vr * wc.z - wr * vc.z + lam * vr * vc.z);
    d.w = (float)NN * (fabsf(p.w) - vr * wc.w - wr * vc.w + lam * vr * vc.w);
    int dd = row - c0;
    if (dd == 0) d.x += EPS_SHIFT;
    else if (dd == 1) d.y += EPS_SHIFT;
    else if (dd == 2) d.z += EPS_SHIFT;
    else if (dd == 3) d.w += EPS_SHIFT;
    ((float4*)D)[idx] = d;
    float ss = d.x * d.x + d.y * d.y + d.z * d.z + d.w * d.w;
    ss = block_sum(ss);
    if (threadIdx.x == 0) atomicAdd(sc, ss);
}

// sc[0]=||D||_F^2, sc[5]=lam~  ->  sc[1]=1/c, sc[2]=sqrt(c), sc[4]=sqrt(N*lam~)
__global__ void finalize_kernel(float* sc) {
    float c = sqrtf(sc[0]);
    sc[1] = 1.f / c;
    sc[2] = sqrtf(c);
    sc[4] = sqrtf((float)NN * sc[5]);
}

// XCD-patch swizzle (bijective). Dispatch round-robins flat id f over 8 XCDs
// (XCD = f&7). Remap so each XCD owns ONE z-slice and a compact tile patch:
//   gz==2 (512 blocks): XCD p -> z=p&1, 8x8 tile patch (quadrant p>>1).
//     per-XCD staging set: 8 tile-rows A + 8 tile-cols B = 4MB (2MB stage1) <= L2.
//   gz==1 (256 blocks): XCD p -> 4x8 patch -> 3MB.
// Was: XCD = bx%8 -> every XCD staged ALL A rows of both z ops (~8.5MB) -> L2
// thrash -> staging at HBM rate (the ~19us/unit R6 measurement).
__device__ __forceinline__ void tile_swizzle64(int& row0, int& col0, int& zz) {
    int f = blockIdx.x + (blockIdx.y << 4) + (blockIdx.z << 8);
    int p = f & 7;
    int i = f >> 3;
    if (gridDim.z == 2) {
        zz = p & 1;
        int s = p >> 1;                        // 0..3 quadrant
        row0 = (((s >> 1) << 3) + (i >> 3)) << 6;
        col0 = (((s & 1) << 3) + (i & 7)) << 6;
    } else {
        zz = 0;                                // i in [0,32)
        row0 = (((p >> 1) << 2) + (i >> 3)) << 6;
        col0 = (((p & 1) << 3) + (i & 7)) << 6;
    }
}

// ---------- MFMA GEMM: 64x64 tile, 128 threads (2 waves), split-bf16 fp32 ----------
// R5 schedule (counted vmcnt, 4 buffers, depth-3 prefetch, raw barrier) +
// R6 transposed emit (CfT) + R7 XCD-patch block swizzle (callers).
__device__ __forceinline__ void mm_dev(const ushort* __restrict__ Ah,
                                       const ushort* __restrict__ Al,
                                       const ushort* __restrict__ Bh,
                                       const ushort* __restrict__ Bl,
                                       int row0, int col0, int kb, int kc,
                                       float* __restrict__ Cf,
                                       float* __restrict__ CfT,
                                       ushort* __restrict__ Chi,
                                       ushort* __restrict__ Clo) {
    // 4 buffers x 4 tiles (Ah,Al,Bh,Bl) x 64x32 bf16 = 64 KiB
    __shared__ __align__(16) ushort lds[4 * 4 * 2048];
    const int t = threadIdx.x;          // 0..127
    const int w = t >> 6, l = t & 63;
    const int fm = l & 15, fq = l >> 4;
    const int lrow = l >> 2;            // 0..15 (rows per 1KB DMA issue)
    const int lcol = (l & 3) << 3;      // 8 bf16 = 16B per lane

    // wave 0 stages the A tiles (hi+lo), wave 1 stages the B tiles
    const ushort* gh = w ? Bh : Ah;
    const ushort* gl = w ? Bl : Al;
    const int r0 = w ? col0 : row0;
    const ushort* ghp = gh + (size_t)(r0 + lrow) * NN + kb + lcol;
    const ushort* glp = gl + (size_t)(r0 + lrow) * NN + kb + lcol;

    floatx4 acc[4][2];
    #pragma unroll
    for (int mi = 0; mi < 4; ++mi) {
        acc[mi][0] = (floatx4)0.f;
        acc[mi][1] = (floatx4)0.f;
    }

    // stage k-step kt (4 tiles, 8 DMA issues per wave) into buffer bufi
    auto STAGE = [&](int bufi, int kt) {
        const int koff = kt << 5;
        ushort* sb = lds + (bufi << 13) + (w << 12);   // this wave's 2 tiles
        #pragma unroll
        for (int rb = 0; rb < 4; ++rb) {               // 16 rows per issue
            gload16(ghp + (size_t)(rb << 4) * NN + koff, sb + (rb << 9));
            gload16(glp + (size_t)(rb << 4) * NN + koff, sb + 2048 + (rb << 9));
        }
    };

    // 24 MFMAs on buffer bufi: acc += Ah*Bh + Al*Bh + Ah*Bl
    auto COMPUTE = [&](int bufi) {
        const ushort* Ash = lds + (bufi << 13);
        const ushort* Asl = Ash + 2048;
        const ushort* Bsh = Ash + 4096;
        const ushort* Bsl = Ash + 6144;
        const int bo = ((w << 5) + fm) * 32 + (fq << 3);
        short8 bh0 = *(const short8*)&Bsh[bo];
        short8 bh1 = *(const short8*)&Bsh[bo + 512];
        short8 bl0 = *(const short8*)&Bsl[bo];
        short8 bl1 = *(const short8*)&Bsl[bo + 512];
        #pragma unroll
        for (int mi = 0; mi < 4; ++mi) {
            const int ao = ((mi << 4) + fm) * 32 + (fq << 3);
            short8 ah = *(const short8*)&Ash[ao];
            short8 al = *(const short8*)&Asl[ao];
            acc[mi][0] = __builtin_amdgcn_mfma_f32_16x16x32_bf16(ah, bh0, acc[mi][0], 0, 0, 0);
            acc[mi][1] = __builtin_amdgcn_mfma_f32_16x16x32_bf16(ah, bh1, acc[mi][1], 0, 0, 0);
            acc[mi][0] = __builtin_amdgcn_mfma_f32_16x16x32_bf16(al, bh0, acc[mi][0], 0, 0, 0);
            acc[mi][1] = __builtin_amdgcn_mfma_f32_16x16x32_bf16(al, bh1, acc[mi][1], 0, 0, 0);
            acc[mi][0] = __builtin_amdgcn_mfma_f32_16x16x32_bf16(ah, bl0, acc[mi][0], 0, 0, 0);
            acc[mi][1] = __builtin_amdgcn_mfma_f32_16x16x32_bf16(ah, bl1, acc[mi][1], 0, 0, 0);
        }
    };

    const int nk = kc >> 5;             // 16 (stage1) or 32 (full K); nk >= 4
    STAGE(0, 0);
    STAGE(1, 1);
    STAGE(2, 2);
    #pragma unroll 1
    for (int kt = 0; kt < nk; ++kt) {
        // wait for stage(kt): keep 2 newer stages (16 loads/wave) in flight
        if (kt + 2 < nk)       asm volatile("s_waitcnt vmcnt(16)" ::: "memory");
        else if (kt + 1 < nk)  asm volatile("s_waitcnt vmcnt(8)"  ::: "memory");
        else                   asm volatile("s_waitcnt vmcnt(0)"  ::: "memory");
        __builtin_amdgcn_s_barrier();            // raw barrier: no vmcnt(0) drain
        __builtin_amdgcn_sched_barrier(0);       // pin: nothing hoists above
        if (kt + 3 < nk) STAGE((kt + 3) & 3, kt + 3);  // into buf (kt-1)%4, free
        COMPUTE(kt & 3);
    }

    // epilogue: C/D layout col=lane&15, row=(lane>>4)*4+reg (m89-verified)
    #pragma unroll
    for (int mi = 0; mi < 4; ++mi) {
        #pragma unroll
        for (int r = 0; r < 4; ++r) {
            int row = row0 + (mi << 4) + (fq << 2) + r;
            #pragma unroll
            for (int ni = 0; ni < 2; ++ni) {
                int col = col0 + (w << 5) + (ni << 4) + fm;
                float v = acc[mi][ni][r];
                size_t idx = (size_t)row * NN + col;
                if (Cf) {
                    Cf[idx] = v;
                } else {
                    ushort h = f2bf(v);
                    Chi[idx] = h;
                    Clo[idx] = f2bf(v - bf2f(h));
                }
            }
        }
    }

    // transposed emit: LDS round-trip, coalesced float4 stores of C^T
    if (CfT) {
        __syncthreads();                 // all waves done with k-loop LDS
        float* lf = (float*)lds;         // [64 cols][stride 68] fp32 = 17.4KB
        #pragma unroll
        for (int mi = 0; mi < 4; ++mi) {
            #pragma unroll
            for (int r = 0; r < 4; ++r) {
                int rl = (mi << 4) + (fq << 2) + r;
                #pragma unroll
                for (int ni = 0; ni < 2; ++ni) {
                    int cl = (w << 5) + (ni << 4) + fm;
                    lf[cl * 68 + rl] = acc[mi][ni][r];
                }
            }
        }
        __syncthreads();
        int c = t >> 1, half = t & 1;
        const float* src = lf + c * 68 + (half << 5);
        float* dst = CfT + (size_t)(col0 + c) * NN + row0 + (half << 5);
        #pragma unroll
        for (int j = 0; j < 8; ++j)
            *(float4*)(dst + (j << 2)) = *(const float4*)(src + (j << 2));
    }
}

// stage-1: Mp[z] = partial (Z*Y) over half the K range; also writes Mp[z]^T
__global__ __launch_bounds__(128) void k_stage1(const ushort* __restrict__ Zh,
                                                const ushort* __restrict__ Zl,
                                                const ushort* __restrict__ Yh,
                                                const ushort* __restrict__ Yl,
                                                float* __restrict__ Mp,
                                                float* __restrict__ MpT0,
                                                float* __restrict__ MpT1) {
    int row0, col0, s;
    tile_swizzle64(row0, col0, s);
    mm_dev(Zh, Zl, Yh, Yl, row0, col0,
           s * (NN / 2), NN / 2, Mp + (size_t)s * NN * NN,
           s ? MpT1 : MpT0, nullptr, nullptr);
}

// stage-2: z=0: Yn = Y*W ; z=1: Zn = W*Z  (epilogue writes bf16 hi/lo directly)
__global__ __launch_bounds__(128) void k_stage2(const ushort* __restrict__ Yh,
                                                const ushort* __restrict__ Yl,
                                                const ushort* __restrict__ Wh,
                                                const ushort* __restrict__ Wl,
                                                const ushort* __restrict__ Zh,
                                                const ushort* __restrict__ Zl,
                                                ushort* __restrict__ Ynh,
                                                ushort* __restrict__ Ynl,
                                                ushort* __restrict__ Znh,
                                                ushort* __restrict__ Znl) {
    int row0, col0, zz;
    tile_swizzle64(row0, col0, zz);
    if (zz == 0)
        mm_dev(Yh, Yl, Wh, Wl, row0, col0, 0, NN,
               nullptr, nullptr, Ynh, Ynl);
    else
        mm_dev(Wh, Wl, Zh, Zl, row0, col0, 0, NN,
               nullptr, nullptr, Znh, Znl);
}

// final: Yf = Y*W in fp32 (+ transpose for k_out1)
__global__ __launch_bounds__(128) void k_final(const ushort* __restrict__ Yh,
                                               const ushort* __restrict__ Yl,
                                               const ushort* __restrict__ Wh,
                                               const ushort* __restrict__ Wl,
                                               float* __restrict__ Yf,
                                               float* __restrict__ YfT) {
    int row0, col0, zz;
    tile_swizzle64(row0, col0, zz);
    mm_dev(Yh, Yl, Wh, Wl, row0, col0, 0, NN,
           Yf, YfT, nullptr, nullptr);
}

// W = 1.5I - 0.25*(Mp0+Mp1+Mp0^T+Mp1^T) -> bf16 hi/lo  (all reads coalesced)
__global__ __launch_bounds__(256) void k_wsplit(const float* __restrict__ Mp,
                                                const float* __restrict__ MpT0,
                                                const float* __restrict__ MpT1,
                                                ushort* __restrict__ Wh,
                                                ushort* __restrict__ Wl) {
    int i = blockIdx.x * 256 + threadIdx.x;     // float4 index over NN*NN/4
    int row = i >> 8, c0 = (i & 255) << 2;
    float4 m0 = ((const float4*)Mp)[i];
    float4 m1 = ((const float4*)Mp)[i + NN * NN / 4];
    float4 t0 = ((const float4*)MpT0)[i];
    float4 t1 = ((const float4*)MpT1)[i];
    float wv[4] = {-0.25f * (m0.x + m1.x + t0.x + t1.x),
                   -0.25f * (m0.y + m1.y + t0.y + t1.y),
                   -0.25f * (m0.z + m1.z + t0.z + t1.z),
                   -0.25f * (m0.w + m1.w + t0.w + t1.w)};
    int dd = row - c0;
    if (dd >= 0 && dd < 4) wv[dd] += 1.5f;
    ushort4 hv, lv;
    ushort* hp = (ushort*)&hv; ushort* lp = (ushort*)&lv;
    #pragma unroll
    for (int j = 0; j < 4; ++j) {
        ushort h = f2bf(wv[j]); hp[j] = h; lp[j] = f2bf(wv[j] - bf2f(h));
    }
    *(ushort4*)&Wh[(size_t)i << 2] = hv;
    *(ushort4*)&Wl[(size_t)i << 2] = lv;
}

// iter0: Y0 = D/c -> split ; W0 = 1.5I - 0.5*Y0 -> split
__global__ __launch_bounds__(256) void k_wsplit0(const float* __restrict__ D,
                                                 const float* __restrict__ sc,
                                                 ushort* __restrict__ Yh,
                                                 ushort* __restrict__ Yl,
                                                 ushort* __restrict__ Wh,
                                                 ushort* __restrict__ Wl) {
    int i = blockIdx.x * 256 + threadIdx.x;
    int row = i >> 8, c0 = (i & 255) << 2;
    float invc = sc[1];
    float4 d = ((const float4*)D)[i];
    float yv[4] = {d.x * invc, d.y * invc, d.z * invc, d.w * invc};
    ushort4 yh, yl, wh, wl;
    ushort* yhp = (ushort*)&yh; ushort* ylp = (ushort*)&yl;
    ushort* whp = (ushort*)&wh; ushort* wlp = (ushort*)&wl;
    int dd = row - c0;
    #pragma unroll
    for (int j = 0; j < 4; ++j) {
        float y = yv[j];
        ushort h = f2bf(y); yhp[j] = h; ylp[j] = f2bf(y - bf2f(h));
        float wv = ((dd == j) ? 1.5f : 0.f) - 0.5f * y;
        ushort h2 = f2bf(wv); whp[j] = h2; wlp[j] = f2bf(wv - bf2f(h2));
    }
    *(ushort4*)&Yh[(size_t)i << 2] = yh;
    *(ushort4*)&Yl[(size_t)i << 2] = yl;
    *(ushort4*)&Wh[(size_t)i << 2] = wh;
    *(ushort4*)&Wl[(size_t)i << 2] = wl;
}

// out0[b][n][m] = d_b[n]*d_b[m] + |P_u[n,m]| + 0.01*Q_k[n,m]^2 ; d_b = x[0,:]-x[b,:]
__global__ __launch_bounds__(256) void out0_kernel(const float* __restrict__ x,
                                                   const float* __restrict__ pu,
                                                   const float* __restrict__ qk,
                                                   float* __restrict__ out) {
    int i = blockIdx.x * blockDim.x + threadIdx.x;  // over BB*NN*NN/4
    int rem = i & (NN * NN / 4 - 1);
    int b = i >> 18;
    int n = rem >> 8;
    int m4 = (rem & 255) << 2;
    float dn = x[n] - x[b * NN + n];
    float4 x0v = *(const float4*)(x + m4);
    float4 xbv = *(const float4*)(x + b * NN + m4);
    float4 pv = ((const float4*)pu)[rem];
    float4 qv = ((const float4*)qk)[rem];
    float4 o;
    o.x = dn * (x0v.x - xbv.x) + fabsf(pv.x) + 0.01f * qv.x * qv.x;
    o.y = dn * (x0v.y - xbv.y) + fabsf(pv.y) + 0.01f * qv.y * qv.y;
    o.z = dn * (x0v.z - xbv.z) + fabsf(pv.z) + 0.01f * qv.z * qv.z;
    o.w = dn * (x0v.w - xbv.w) + fabsf(pv.w) + 0.01f * qv.w * qv.w;
    ((float4*)out)[i] = o;
}

// fused sym + out1: p[j][i] = 0.5*sqrt(c)*(Yf[j][i]+YfT[j][i]) + sqrt(N*lam)*v[j]*v[i]
// out1[0][b][j][i] = x[b][i] + p ; out1[0][b][N+j][i] = x[b][i] - p
__global__ __launch_bounds__(256) void k_out1(const float* __restrict__ x,
                                              const float* __restrict__ Yf,
                                              const float* __restrict__ YfT,
                                              const float* __restrict__ sc,
                                              const float* __restrict__ v,
                                              float* __restrict__ out1) {
    int i = blockIdx.x * 256 + threadIdx.x;     // over NN*NN/4
    int j = i >> 8, i0 = (i & 255) << 2;
    float s = 0.5f * sc[2], s1v = sc[4] * v[j];
    float4 yr = *(const float4*)(Yf + (size_t)j * NN + i0);
    float4 yc = *(const float4*)(YfT + (size_t)j * NN + i0);
    float4 vc = *(const float4*)(v + i0);
    float4 p;
    p.x = s * (yr.x + yc.x) + s1v * vc.x;
    p.y = s * (yr.y + yc.y) + s1v * vc.y;
    p.z = s * (yr.z + yc.z) + s1v * vc.z;
    p.w = s * (yr.w + yc.w) + s1v * vc.w;
    #pragma unroll
    for (int b = 0; b < BB; ++b) {
        float4 xv = *(const float4*)(x + b * NN + i0);
        float4 a, m;
        a.x = xv.x + p.x; a.y = xv.y + p.y; a.z = xv.z + p.z; a.w = xv.w + p.w;
        m.x = xv.x - p.x; m.y = xv.y - p.y; m.z = xv.z - p.z; m.w = xv.w - p.w;
        float* base = out1 + (size_t)b * 2 * NN * NN;
        *(float4*)(base + (size_t)j * NN + i0) = a;
        *(float4*)(base + (size_t)(NN + j) * NN + i0) = m;
    }
}

extern "C" void kernel_launch(void* const* d_in, const int* in_sizes, int n_in,
                              void* d_out, int out_size, void* d_ws, size_t ws_size,
                              hipStream_t stream) {
    const float* x  = (const float*)d_in[0];
    const float* pu = (const float*)d_in[1];
    const float* qk = (const float*)d_in[2];
    float* out = (float*)d_out;
    char* ws = (char*)d_ws;

    // layout: [0,8MB) fp32 Mp0/Mp1 (Mp0 doubles as D before iter1 and Yf after
    // last wsplit; Mp1 doubles as YfT after the last wsplit);
    // [8MB,28MB) five bf16 hi/lo pairs (4MB each); vectors after.
    float* Mp = (float*)ws;
    float* D  = Mp;
    float* Yf = Mp;
    float* YfT = (float*)(ws + (size_t)4 * MB);
    ushort* hi[5]; ushort* lo[5];
    for (int k = 0; k < 5; ++k) {
        hi[k] = (ushort*)(ws + (size_t)8 * MB + (size_t)k * 4 * MB);
        lo[k] = (ushort*)(ws + (size_t)8 * MB + (size_t)k * 4 * MB + 2 * MB);
    }
    float* vv = (float*)(ws + (size_t)28 * MB);
    float* vw = (float*)(ws + (size_t)28 * MB + 4096);
    float* vt = (float*)(ws + (size_t)28 * MB + 8192);
    float* sc = (float*)(ws + (size_t)28 * MB + 12288);

    // ---- deflation: top eigpair of |P_u| via 3 matvecs ----
    hipMemsetAsync(sc, 0, 64, stream);
    matvec_abs<<<NN, 256, 0, stream>>>(pu, vv, vt, 1);
    norm_vec<<<1, 256, 0, stream>>>(vt, vv);
    matvec_abs<<<NN, 256, 0, stream>>>(pu, vv, vt, 0);
    norm_vec<<<1, 256, 0, stream>>>(vt, vv);
    matvec_abs<<<NN, 256, 0, stream>>>(pu, vv, vw, 0);
    dot_vec<<<1, 256, 0, stream>>>(vv, vw, sc + 5);
    deflate_kernel<<<NN * NN / 4 / 256, 256, 0, stream>>>(pu, vv, vw, sc, D);
    finalize_kernel<<<1, 1, 0, stream>>>(sc);

    // ---- iter 0: Y0,W0 from D; Y1 = Y0*W0 ; Z1 = W0 (pointer swap) ----
    k_wsplit0<<<NN * NN / 4 / 256, 256, 0, stream>>>(D, sc, hi[0], lo[0], hi[1], lo[1]);
    k_stage2<<<dim3(16, 16, 1), 128, 0, stream>>>(hi[0], lo[0], hi[1], lo[1],
                                                  hi[0], lo[0],   // Z unused (zz=0 only)
                                                  hi[2], lo[2], hi[3], lo[3]);
    int Y = 2, Z = 1, f0 = 0, f1 = 3, f2 = 4;

    // ---- iters 1..NS_ITERS-1 ----
    for (int it = 1; it < NS_ITERS; ++it) {
        int W = f0;
        // MpT0/MpT1 scratch: the f1/f2 buffer regions (dead until stage2 writes
        // them, and k_wsplit reads them strictly before that in stream order)
        float* MpT0 = (float*)hi[f1];
        float* MpT1 = (float*)hi[f2];
        k_stage1<<<dim3(16, 16, 2), 128, 0, stream>>>(hi[Z], lo[Z], hi[Y], lo[Y],
                                                      Mp, MpT0, MpT1);
        k_wsplit<<<NN * NN / 4 / 256, 256, 0, stream>>>(Mp, MpT0, MpT1,
                                                        hi[W], lo[W]);
        if (it + 1 < NS_ITERS) {
            int Yn = f1, Zn = f2;
            k_stage2<<<dim3(16, 16, 2), 128, 0, stream>>>(
                hi[Y], lo[Y], hi[W], lo[W], hi[Z], lo[Z],
                hi[Yn], lo[Yn], hi[Zn], lo[Zn]);
            f0 = Y; f1 = Z; f2 = W;
            Y = Yn; Z = Zn;
        } else {
            k_final<<<dim3(16, 16, 1), 128, 0, stream>>>(hi[Y], lo[Y], hi[W], lo[W],
                                                         Yf, YfT);
        }
    }

    // ---- outputs ----
    out0_kernel<<<(BB * NN * NN / 4) / 256, 256, 0, stream>>>(x, pu, qk, out);
    k_out1<<<NN * NN / 4 / 256, 256, 0, stream>>>(x, Yf, YfT, sc, vv,
                                                  out + (size_t)BB * NN * NN);
}